// Round 3
// baseline (719.875 us; speedup 1.0000x reference)
//
#include <hip/hip_runtime.h>
#include <cstdint>
#include <cstddef>

typedef __bf16 bf16;
typedef __bf16 bf16x8 __attribute__((ext_vector_type(8)));
typedef float f32x4 __attribute__((ext_vector_type(4)));

#define TOKENS 4096   // B*T
#define TSEQ   2048
#define NHEADS 16
#define HDIM   64
#define CDIM   1024

// ------------------------------------------------------------------
// Input dtype detection (insurance; expected: all fp32 -> flag 0).
// For bf16 data, word bits 7..14 are the low element's exponent field
// (in [100,140] for ~all normal-scale data); for fp32 they are mantissa
// noise (~16% hit rate). All-zero samples -> bf16 copy path (safe).
// ------------------------------------------------------------------
#define NBUF 17
struct DetectArgs { const void* p[NBUF]; int n[NBUF]; };

__global__ __launch_bounds__(256) void detect_kernel(DetectArgs a, int* __restrict__ flags) {
  __shared__ int s_nz, s_bl;
  if (threadIdx.x == 0) { s_nz = 0; s_bl = 0; }
  __syncthreads();
  int i = blockIdx.x;
  const unsigned int* w = (const unsigned int*)a.p[i];
  int nwords = a.n[i] / 2; if (nwords > 2048) nwords = 2048;
  int nz = 0, bl = 0;
  for (int j = threadIdx.x; j < nwords; j += 256) {
    unsigned int v = w[j];
    if (v != 0u) {
      nz++;
      unsigned int e = (v >> 7) & 0xFFu;
      if (e >= 100u && e <= 140u) bl++;
    }
  }
  atomicAdd(&s_nz, nz);
  atomicAdd(&s_bl, bl);
  __syncthreads();
  if (threadIdx.x == 0) flags[i] = (2 * s_bl >= s_nz) ? 1 : 0;  // 1 = already bf16
}

__global__ __launch_bounds__(256) void convert_to_bf16(const void* __restrict__ in,
                                                       bf16* __restrict__ out,
                                                       int count, const int* __restrict__ flag) {
  int i = blockIdx.x * 256 + threadIdx.x;
  if (i >= count) return;
  if (*flag) out[i] = ((const bf16*)in)[i];
  else       out[i] = (bf16)(((const float*)in)[i]);
}

// ------------------------------------------------------------------
// Weight transpose: in[K][N] -> out[N][K]  (bf16)
// ------------------------------------------------------------------
__global__ __launch_bounds__(256) void transpose_bf16(const bf16* __restrict__ in,
                                                      bf16* __restrict__ out,
                                                      int K, int N) {
  __shared__ bf16 tile[64][65];
  int kb = blockIdx.y * 64, nb = blockIdx.x * 64;
  int tx = threadIdx.x, ty = threadIdx.y;   // blockDim (64,4)
  for (int i = ty; i < 64; i += 4)
    tile[i][tx] = in[(size_t)(kb + i) * N + nb + tx];
  __syncthreads();
  for (int i = ty; i < 64; i += 4)
    out[(size_t)(nb + i) * K + kb + tx] = tile[tx][i];
}

// ------------------------------------------------------------------
// LayerNorm over rows of 1024, InT in / bf16 out, fp32 math
// ------------------------------------------------------------------
template <typename InT>
__global__ __launch_bounds__(256) void ln_kernel(const InT* __restrict__ x,
                                                 const bf16* __restrict__ g,
                                                 const bf16* __restrict__ b,
                                                 bf16* __restrict__ y) {
  int row = blockIdx.x;
  int tid = threadIdx.x;
  const InT* xr = x + (size_t)row * CDIM;
  float v[4];
  float s = 0.f, s2 = 0.f;
#pragma unroll
  for (int i = 0; i < 4; i++) {
    float f = (float)xr[tid * 4 + i];
    v[i] = f; s += f; s2 += f * f;
  }
#pragma unroll
  for (int off = 32; off; off >>= 1) {
    s  += __shfl_down(s, off);
    s2 += __shfl_down(s2, off);
  }
  __shared__ float red[8];
  int w = tid >> 6;
  if ((tid & 63) == 0) { red[w] = s; red[4 + w] = s2; }
  __syncthreads();
  if (tid == 0) {
    red[0] = red[0] + red[1] + red[2] + red[3];
    red[4] = red[4] + red[5] + red[6] + red[7];
  }
  __syncthreads();
  float mu  = red[0] * (1.0f / CDIM);
  float var = fmaxf(red[4] * (1.0f / CDIM) - mu * mu, 0.f);
  float rstd = rsqrtf(var + 1e-5f);
  bf16* yr = y + (size_t)row * CDIM;
#pragma unroll
  for (int i = 0; i < 4; i++) {
    int c = tid * 4 + i;
    float o = (v[i] - mu) * rstd * (float)g[c] + (float)b[c];
    yr[c] = (bf16)o;
  }
}

// ------------------------------------------------------------------
// MFMA GEMM:  C[M,N] = A[M,K] @ Bt[N,K]^T + bias (+ res) (+ gelu)
// Tile 64x64, BK=32, 4 waves, each 32x32 (2x2 of 16x16x32).
//   A frag : a[j] = A[m = lane&15][k = (lane>>4)*8 + j]
//   B frag : b[j] = B[k = (lane>>4)*8 + j][n = lane&15]
//   C/D    : c[r] = C[row = (lane>>4)*4 + r][col = lane&15]
// ------------------------------------------------------------------
#define EPI_NONE 0
#define EPI_RES  1
#define EPI_GELU 2

template <int EPI, typename OutT, typename ResT>
__global__ __launch_bounds__(256) void gemm_bt(const bf16* __restrict__ A,
                                               const bf16* __restrict__ Bt,
                                               const bf16* __restrict__ bias,
                                               const ResT* __restrict__ res,
                                               OutT* __restrict__ C,
                                               int N, int K) {
  __shared__ alignas(16) bf16 As[64][40];
  __shared__ alignas(16) bf16 Bs[64][40];
  int m0 = blockIdx.y * 64, n0 = blockIdx.x * 64;
  int tid  = threadIdx.x;
  int wave = tid >> 6, lane = tid & 63;
  int quad = lane >> 4, l16 = lane & 15;
  int wm = (wave & 1) * 32, wn = (wave >> 1) * 32;

  f32x4 acc[2][2] = {};

  int ldrow = tid >> 2;          // 64 rows
  int ldcol = (tid & 3) * 8;     // 4 chunks of 8 bf16 (16B)

  for (int k0 = 0; k0 < K; k0 += 32) {
    *(bf16x8*)&As[ldrow][ldcol] = *(const bf16x8*)&A[(size_t)(m0 + ldrow) * K + k0 + ldcol];
    *(bf16x8*)&Bs[ldrow][ldcol] = *(const bf16x8*)&Bt[(size_t)(n0 + ldrow) * K + k0 + ldcol];
    __syncthreads();

    bf16x8 af[2], bfr[2];
    af[0]  = *(const bf16x8*)&As[wm + l16][quad * 8];
    af[1]  = *(const bf16x8*)&As[wm + 16 + l16][quad * 8];
    bfr[0] = *(const bf16x8*)&Bs[wn + l16][quad * 8];
    bfr[1] = *(const bf16x8*)&Bs[wn + 16 + l16][quad * 8];
#pragma unroll
    for (int si = 0; si < 2; si++)
#pragma unroll
      for (int sj = 0; sj < 2; sj++)
        acc[si][sj] = __builtin_amdgcn_mfma_f32_16x16x32_bf16(af[si], bfr[sj], acc[si][sj], 0, 0, 0);
    __syncthreads();
  }

#pragma unroll
  for (int si = 0; si < 2; si++) {
#pragma unroll
    for (int sj = 0; sj < 2; sj++) {
      int n = n0 + wn + sj * 16 + l16;
      float bv = (float)bias[n];
#pragma unroll
      for (int r = 0; r < 4; r++) {
        int m = m0 + wm + si * 16 + quad * 4 + r;
        float v = acc[si][sj][r] + bv;
        if (EPI == EPI_GELU) {
          v = 0.5f * v * (1.0f + erff(v * 0.70710678118654752f));
        } else if (EPI == EPI_RES) {
          v += (float)res[(size_t)m * N + n];
        }
        C[(size_t)m * N + n] = (OutT)v;
      }
    }
  }
}

// ------------------------------------------------------------------
// Flash attention: 1 wave per (b, h, 16-query tile). Key tiles of 32.
// ------------------------------------------------------------------
__global__ __launch_bounds__(64) void attn_kernel(const bf16* __restrict__ Q,
                                                  const bf16* __restrict__ Kb,
                                                  const bf16* __restrict__ Vb,
                                                  bf16* __restrict__ O) {
  int b = blockIdx.z, h = blockIdx.y, q0 = blockIdx.x * 16;
  int lane = threadIdx.x, quad = lane >> 4, l16 = lane & 15;

  __shared__ alignas(16) bf16 Vt[64][40];   // Vt[d][key]
  __shared__ alignas(16) bf16 Pt[16][40];   // Pt[qrow][key]

  const bf16* qp = Q + ((size_t)(b * TSEQ + q0)) * CDIM + h * HDIM;
  bf16x8 aq[2];
  aq[0] = *(const bf16x8*)&qp[(size_t)l16 * CDIM + quad * 8];
  aq[1] = *(const bf16x8*)&qp[(size_t)l16 * CDIM + 32 + quad * 8];

  float m_i[4], l_i[4];
  f32x4 accO[4] = {};
#pragma unroll
  for (int r = 0; r < 4; r++) { m_i[r] = -1e30f; l_i[r] = 0.f; }

  const float scale = 0.125f;   // 1/sqrt(64)

  for (int t0 = 0; t0 < TSEQ; t0 += 32) {
    f32x4 S[2];
#pragma unroll
    for (int c = 0; c < 2; c++) {
      const bf16* kp = Kb + ((size_t)(b * TSEQ + t0 + c * 16 + l16)) * CDIM + h * HDIM;
      f32x4 s = {};
      s = __builtin_amdgcn_mfma_f32_16x16x32_bf16(aq[0], *(const bf16x8*)&kp[quad * 8], s, 0, 0, 0);
      s = __builtin_amdgcn_mfma_f32_16x16x32_bf16(aq[1], *(const bf16x8*)&kp[32 + quad * 8], s, 0, 0, 0);
      S[c] = s;
    }

    {
      int key = lane & 31, dh = (lane >> 5) * 32;
      const bf16* vp = Vb + ((size_t)(b * TSEQ + t0 + key)) * CDIM + h * HDIM + dh;
#pragma unroll
      for (int i = 0; i < 32; i += 8) {
        bf16x8 vv = *(const bf16x8*)&vp[i];
#pragma unroll
        for (int j = 0; j < 8; j++) Vt[dh + i + j][key] = vv[j];
      }
    }

    float alpha[4];
#pragma unroll
    for (int r = 0; r < 4; r++) {
      float s0 = S[0][r] * scale, s1 = S[1][r] * scale;
      float mx = fmaxf(s0, s1);
#pragma unroll
      for (int off = 1; off < 16; off <<= 1) mx = fmaxf(mx, __shfl_xor(mx, off));
      float mnew = fmaxf(m_i[r], mx);
      alpha[r] = __expf(m_i[r] - mnew);
      m_i[r] = mnew;
      float p0 = __expf(s0 - mnew), p1 = __expf(s1 - mnew);
      float rs = p0 + p1;
#pragma unroll
      for (int off = 1; off < 16; off <<= 1) rs += __shfl_xor(rs, off);
      l_i[r] = l_i[r] * alpha[r] + rs;
      Pt[quad * 4 + r][l16] = (bf16)p0;
      Pt[quad * 4 + r][16 + l16] = (bf16)p1;
    }
    __syncthreads();

    bf16x8 pa = *(const bf16x8*)&Pt[l16][quad * 8];
    bf16x8 bv[4];
#pragma unroll
    for (int ds = 0; ds < 4; ds++)
      bv[ds] = *(const bf16x8*)&Vt[ds * 16 + l16][quad * 8];
#pragma unroll
    for (int ds = 0; ds < 4; ds++) {
#pragma unroll
      for (int r = 0; r < 4; r++) accO[ds][r] *= alpha[r];
      accO[ds] = __builtin_amdgcn_mfma_f32_16x16x32_bf16(pa, bv[ds], accO[ds], 0, 0, 0);
    }
    __syncthreads();
  }

#pragma unroll
  for (int ds = 0; ds < 4; ds++) {
#pragma unroll
    for (int r = 0; r < 4; r++) {
      float v = accO[ds][r] / fmaxf(l_i[r], 1e-30f);
      O[((size_t)(b * TSEQ + q0 + quad * 4 + r)) * CDIM + h * HDIM + ds * 16 + l16] = (bf16)v;
    }
  }
}

// ------------------------------------------------------------------
extern "C" void kernel_launch(void* const* d_in, const int* in_sizes, int n_in,
                              void* d_out, int out_size, void* d_ws, size_t ws_size,
                              hipStream_t stream) {
  char* ws = (char*)d_ws;
  const size_t MB = 1024 * 1024;
  const size_t KB = 1024;

  int* flags = (int*)ws;                          // 17 ints
  bf16* vec_c = (bf16*)(ws + 4 * KB);             // 10 vectors x 16KB
  bf16* ln1g_c = vec_c + 0 * 8192;
  bf16* ln1b_c = vec_c + 1 * 8192;
  bf16* ln2g_c = vec_c + 2 * 8192;
  bf16* ln2b_c = vec_c + 3 * 8192;
  bf16* bq_c   = vec_c + 4 * 8192;
  bf16* bk_c   = vec_c + 5 * 8192;
  bf16* bv_c   = vec_c + 6 * 8192;
  bf16* bo_c   = vec_c + 7 * 8192;
  bf16* b1_c   = vec_c + 8 * 8192;
  bf16* b2_c   = vec_c + 9 * 8192;

  bf16*  x_c    = (bf16*)(ws + 1 * MB);           // 1-9
  bf16*  Wq_c   = (bf16*)(ws + 9 * MB);           // 9-11   (dead after transpose)
  bf16*  Wk_c   = (bf16*)(ws + 11 * MB);          // 11-13
  bf16*  Wv_c   = (bf16*)(ws + 13 * MB);          // 13-15
  bf16*  Wo_c   = (bf16*)(ws + 15 * MB);          // 15-17
  bf16*  W1_c   = (bf16*)(ws + 17 * MB);          // 17-25
  bf16*  W2_c   = (bf16*)(ws + 25 * MB);          // 25-33
  float* xmid32 = (float*)(ws + 9 * MB);          // 9-25 fp32 (reuses dead converts)
  bf16*  WqT    = (bf16*)(ws + 33 * MB);
  bf16*  WkT    = (bf16*)(ws + 35 * MB);
  bf16*  WvT    = (bf16*)(ws + 37 * MB);
  bf16*  WoT    = (bf16*)(ws + 39 * MB);
  bf16*  W1T    = (bf16*)(ws + 41 * MB);          // 41-49
  bf16*  W2T    = (bf16*)(ws + 49 * MB);          // 49-57
  bf16*  xn     = (bf16*)(ws + 57 * MB);          // 57-65  (ln1 out; later h2)
  bf16*  qb     = (bf16*)(ws + 65 * MB);          // 65-73
  bf16*  kbuf   = (bf16*)(ws + 73 * MB);          // 73-81
  bf16*  vbuf   = (bf16*)(ws + 81 * MB);          // 81-89
  bf16*  ab     = (bf16*)(ws + 89 * MB);          // 89-97
  bf16*  f1     = qb;                             // 65-97 (32MB, reuse)
  bf16*  h2     = xn;                             // 57-65 (reuse)

  // ---- detect input dtypes ----
  const int din_idx[NBUF] = {0, 2, 3, 4, 5, 6, 7, 8, 9, 10, 11, 12, 13, 14, 15, 16, 17};
  DetectArgs da;
  for (int i = 0; i < NBUF; i++) { da.p[i] = d_in[din_idx[i]]; da.n[i] = in_sizes[din_idx[i]]; }
  detect_kernel<<<NBUF, 256, 0, stream>>>(da, flags);

  // ---- convert all float inputs to guaranteed-bf16 ----
  bf16* dsts[NBUF] = {x_c, ln1g_c, ln1b_c, ln2g_c, ln2b_c, Wq_c, bq_c, Wk_c, bk_c,
                      Wv_c, bv_c, Wo_c, bo_c, W1_c, b1_c, W2_c, b2_c};
  for (int i = 0; i < NBUF; i++) {
    int cnt = in_sizes[din_idx[i]];
    convert_to_bf16<<<(cnt + 255) / 256, 256, 0, stream>>>(d_in[din_idx[i]], dsts[i], cnt, flags + i);
  }

  // ---- transpose weights ----
  dim3 tb(64, 4);
  transpose_bf16<<<dim3(16, 16), tb, 0, stream>>>(Wq_c, WqT, 1024, 1024);
  transpose_bf16<<<dim3(16, 16), tb, 0, stream>>>(Wk_c, WkT, 1024, 1024);
  transpose_bf16<<<dim3(16, 16), tb, 0, stream>>>(Wv_c, WvT, 1024, 1024);
  transpose_bf16<<<dim3(16, 16), tb, 0, stream>>>(Wo_c, WoT, 1024, 1024);
  transpose_bf16<<<dim3(64, 16), tb, 0, stream>>>(W1_c, W1T, 1024, 4096);
  transpose_bf16<<<dim3(16, 64), tb, 0, stream>>>(W2_c, W2T, 4096, 1024);

  // ---- pipeline ----
  ln_kernel<bf16><<<TOKENS, 256, 0, stream>>>(x_c, ln1g_c, ln1b_c, xn);

  gemm_bt<EPI_NONE, bf16, bf16><<<dim3(16, 64), 256, 0, stream>>>(xn, WqT, bq_c, (const bf16*)nullptr, qb, 1024, 1024);
  gemm_bt<EPI_NONE, bf16, bf16><<<dim3(16, 64), 256, 0, stream>>>(xn, WkT, bk_c, (const bf16*)nullptr, kbuf, 1024, 1024);
  gemm_bt<EPI_NONE, bf16, bf16><<<dim3(16, 64), 256, 0, stream>>>(xn, WvT, bv_c, (const bf16*)nullptr, vbuf, 1024, 1024);

  attn_kernel<<<dim3(TSEQ / 16, NHEADS, 2), 64, 0, stream>>>(qb, kbuf, vbuf, ab);

  // xmid (fp32) = ab@Wo + bo + xn   (overwrites dead Wq_c..W1_c region)
  gemm_bt<EPI_RES, float, bf16><<<dim3(16, 64), 256, 0, stream>>>(ab, WoT, bo_c, xn, xmid32, 1024, 1024);

  ln_kernel<float><<<TOKENS, 256, 0, stream>>>(xmid32, ln2g_c, ln2b_c, h2);

  gemm_bt<EPI_GELU, bf16, bf16><<<dim3(64, 64), 256, 0, stream>>>(h2, W1T, b1_c, (const bf16*)nullptr, f1, 4096, 1024);
  gemm_bt<EPI_RES, float, float><<<dim3(16, 64), 256, 0, stream>>>(f1, W2T, b2_c, xmid32, (float*)d_out, 1024, 4096);
}

// Round 5
// 537.445 us; speedup vs baseline: 1.3394x; 1.3394x over previous
//
#include <hip/hip_runtime.h>
#include <cstdint>
#include <cstddef>

typedef __bf16 bf16;
typedef __bf16 bf16x8 __attribute__((ext_vector_type(8)));
typedef __bf16 bf16x4 __attribute__((ext_vector_type(4)));
typedef float f32x4 __attribute__((ext_vector_type(4)));

#define TOKENS 4096   // B*T
#define TSEQ   2048
#define NHEADS 16
#define HDIM   64
#define CDIM   1024

// ---- async global->LDS, 16B per lane ----
typedef __attribute__((address_space(3))) unsigned int lds_uint;
typedef __attribute__((address_space(1))) const unsigned int g_uint;
__device__ __forceinline__ void glds16(const bf16* g, bf16* l) {
  __builtin_amdgcn_global_load_lds((g_uint*)g, (lds_uint*)l, 16, 0, 0);
}

// ------------------------------------------------------------------
// Input dtype detection (insurance; fp32 -> flag 0). See round-2 note.
// ------------------------------------------------------------------
#define NBUF 17
struct DetectArgs { const void* p[NBUF]; int n[NBUF]; };

__global__ __launch_bounds__(256) void detect_kernel(DetectArgs a, int* __restrict__ flags) {
  __shared__ int s_nz, s_bl;
  if (threadIdx.x == 0) { s_nz = 0; s_bl = 0; }
  __syncthreads();
  int i = blockIdx.x;
  const unsigned int* w = (const unsigned int*)a.p[i];
  int nwords = a.n[i] / 2; if (nwords > 2048) nwords = 2048;
  int nz = 0, bl = 0;
  for (int j = threadIdx.x; j < nwords; j += 256) {
    unsigned int v = w[j];
    if (v != 0u) {
      nz++;
      unsigned int e = (v >> 7) & 0xFFu;
      if (e >= 100u && e <= 140u) bl++;
    }
  }
  atomicAdd(&s_nz, nz);
  atomicAdd(&s_bl, bl);
  __syncthreads();
  if (threadIdx.x == 0) flags[i] = (2 * s_bl >= s_nz) ? 1 : 0;
}

__global__ __launch_bounds__(256) void convert_to_bf16(const void* __restrict__ in,
                                                       bf16* __restrict__ out,
                                                       int count, const int* __restrict__ flag) {
  int i = blockIdx.x * 256 + threadIdx.x;
  if (i >= count) return;
  if (*flag) out[i] = ((const bf16*)in)[i];
  else       out[i] = (bf16)(((const float*)in)[i]);
}

// ------------------------------------------------------------------
// Weight transpose: in[K][N] -> out[N][K]  (bf16)
// ------------------------------------------------------------------
__global__ __launch_bounds__(256) void transpose_bf16(const bf16* __restrict__ in,
                                                      bf16* __restrict__ out,
                                                      int K, int N) {
  __shared__ bf16 tile[64][65];
  int kb = blockIdx.y * 64, nb = blockIdx.x * 64;
  int tx = threadIdx.x, ty = threadIdx.y;   // blockDim (64,4)
  for (int i = ty; i < 64; i += 4)
    tile[i][tx] = in[(size_t)(kb + i) * N + nb + tx];
  __syncthreads();
  for (int i = ty; i < 64; i += 4)
    out[(size_t)(nb + i) * K + kb + tx] = tile[tx][i];
}

// ------------------------------------------------------------------
// LayerNorm rows of 1024, InT in / bf16 out, fp32 math
// ------------------------------------------------------------------
template <typename InT>
__global__ __launch_bounds__(256) void ln_kernel(const InT* __restrict__ x,
                                                 const bf16* __restrict__ g,
                                                 const bf16* __restrict__ b,
                                                 bf16* __restrict__ y) {
  int row = blockIdx.x;
  int tid = threadIdx.x;
  const InT* xr = x + (size_t)row * CDIM;
  float v[4];
  float s = 0.f, s2 = 0.f;
#pragma unroll
  for (int i = 0; i < 4; i++) {
    float f = (float)xr[tid * 4 + i];
    v[i] = f; s += f; s2 += f * f;
  }
#pragma unroll
  for (int off = 32; off; off >>= 1) {
    s  += __shfl_down(s, off);
    s2 += __shfl_down(s2, off);
  }
  __shared__ float red[8];
  int w = tid >> 6;
  if ((tid & 63) == 0) { red[w] = s; red[4 + w] = s2; }
  __syncthreads();
  if (tid == 0) {
    red[0] = red[0] + red[1] + red[2] + red[3];
    red[4] = red[4] + red[5] + red[6] + red[7];
  }
  __syncthreads();
  float mu  = red[0] * (1.0f / CDIM);
  float var = fmaxf(red[4] * (1.0f / CDIM) - mu * mu, 0.f);
  float rstd = rsqrtf(var + 1e-5f);
  bf16* yr = y + (size_t)row * CDIM;
#pragma unroll
  for (int i = 0; i < 4; i++) {
    int c = tid * 4 + i;
    float o = (v[i] - mu) * rstd * (float)g[c] + (float)b[c];
    yr[c] = (bf16)o;
  }
}

// ------------------------------------------------------------------
// m97-style GEMM core: C = A[M,K] @ Bt[N,K]^T, tile BM x BN, BK=32,
// 256 threads (4 waves, each (BM/2)x(BN/2)). global_load_lds staging,
// flat LDS layout with XOR chunk swizzle (chunk ^ ((row>>1)&3)) so
// fragment ds_read_b128 is 2-way-conflict-free (free per m136).
//   A frag : a[j] = A[m = lane&15][k = quad*8 + j]
//   B frag : b[j] = Bt[n = lane&15][k = quad*8 + j]
//   C/D    : c[r] = C[row = quad*4 + r][col = lane&15]
// ------------------------------------------------------------------
template <int BM, int BN>
__device__ __forceinline__ void gemm_core(const bf16* __restrict__ A,
                                          const bf16* __restrict__ Bt,
                                          int K, int m0, int n0,
                                          bf16* As, bf16* Bs,
                                          f32x4 (&acc)[BM / 32][BN / 32]) {
  constexpr int SI = BM / 32, SJ = BN / 32;
  int t = threadIdx.x;
  int wave = t >> 6, lane = t & 63, quad = lane >> 4, l16 = lane & 15;
  int wm = (wave & 1) * (BM / 2), wn = (wave >> 1) * (BN / 2);
  int srow = t >> 2, sc = t & 3;            // staging: 64 rows x 4 x 16B per issue
  int swz = (srow >> 1) & 3;                // same for srow+64
  const bf16* ga[BM / 64];
  const bf16* gb[BN / 64];
#pragma unroll
  for (int h = 0; h < BM / 64; h++)
    ga[h] = A + (size_t)(m0 + h * 64 + srow) * K + (sc ^ swz) * 8;
#pragma unroll
  for (int h = 0; h < BN / 64; h++)
    gb[h] = Bt + (size_t)(n0 + h * 64 + srow) * K + (sc ^ swz) * 8;

  for (int k0 = 0; k0 < K; k0 += 32) {
#pragma unroll
    for (int h = 0; h < BM / 64; h++)
      glds16(ga[h] + k0, As + h * 2048 + srow * 32 + sc * 8);
#pragma unroll
    for (int h = 0; h < BN / 64; h++)
      glds16(gb[h] + k0, Bs + h * 2048 + srow * 32 + sc * 8);
    __syncthreads();

    bf16x8 af[SI], bfr[SJ];
#pragma unroll
    for (int i = 0; i < SI; i++) {
      int m = wm + i * 16 + l16;
      af[i] = *(const bf16x8*)&As[m * 32 + ((quad ^ ((m >> 1) & 3)) * 8)];
    }
#pragma unroll
    for (int j = 0; j < SJ; j++) {
      int n = wn + j * 16 + l16;
      bfr[j] = *(const bf16x8*)&Bs[n * 32 + ((quad ^ ((n >> 1) & 3)) * 8)];
    }
#pragma unroll
    for (int i = 0; i < SI; i++)
#pragma unroll
      for (int j = 0; j < SJ; j++)
        acc[i][j] = __builtin_amdgcn_mfma_f32_16x16x32_bf16(af[i], bfr[j], acc[i][j], 0, 0, 0);
    __syncthreads();
  }
}

#define EPI_NONE 0
#define EPI_RES  1
#define EPI_GELU 2

template <int BM, int BN, int EPI, typename OutT, typename ResT>
__global__ __launch_bounds__(256) void gemm128(const bf16* __restrict__ A,
                                               const bf16* __restrict__ Bt,
                                               const bf16* __restrict__ bias,
                                               const ResT* __restrict__ res,
                                               OutT* __restrict__ C,
                                               int N, int K) {
  __shared__ alignas(16) bf16 As[BM * 32];
  __shared__ alignas(16) bf16 Bs[BN * 32];
  int m0 = blockIdx.y * BM, n0 = blockIdx.x * BN;
  f32x4 acc[BM / 32][BN / 32] = {};
  gemm_core<BM, BN>(A, Bt, K, m0, n0, As, Bs, acc);

  int t = threadIdx.x, wave = t >> 6, lane = t & 63, quad = lane >> 4, l16 = lane & 15;
  int wm = (wave & 1) * (BM / 2), wn = (wave >> 1) * (BN / 2);
#pragma unroll
  for (int i = 0; i < BM / 32; i++)
#pragma unroll
    for (int j = 0; j < BN / 32; j++) {
      int n = n0 + wn + j * 16 + l16;
      float bv = (float)bias[n];
#pragma unroll
      for (int r = 0; r < 4; r++) {
        int m = m0 + wm + i * 16 + quad * 4 + r;
        float v = acc[i][j][r] + bv;
        if (EPI == EPI_GELU)      v = 0.5f * v * (1.0f + erff(v * 0.70710678118654752f));
        else if (EPI == EPI_RES)  v += (float)res[(size_t)m * N + n];
        C[(size_t)m * N + n] = (OutT)v;
      }
    }
}

// QKV GEMM: A[4096,1024] @ WqkvT[3072,1024]^T. Cols 0-2047 -> QK buffer
// (natural [token][2048]); cols 2048-3071 (V) -> transposed Vt[1024][4096].
__global__ __launch_bounds__(256) void gemm_qkv(const bf16* __restrict__ A,
                                                const bf16* __restrict__ Bt,
                                                const bf16* __restrict__ bias,
                                                bf16* __restrict__ QK,
                                                bf16* __restrict__ Vt) {
  __shared__ alignas(16) bf16 As[128 * 32];
  __shared__ alignas(16) bf16 Bs[128 * 32];
  int m0 = blockIdx.y * 128, n0 = blockIdx.x * 128;
  f32x4 acc[4][4] = {};
  gemm_core<128, 128>(A, Bt, 1024, m0, n0, As, Bs, acc);

  int t = threadIdx.x, wave = t >> 6, lane = t & 63, quad = lane >> 4, l16 = lane & 15;
  int wm = (wave & 1) * 64, wn = (wave >> 1) * 64;
#pragma unroll
  for (int i = 0; i < 4; i++)
#pragma unroll
    for (int j = 0; j < 4; j++) {
      int n = n0 + wn + j * 16 + l16;
      float bv = (float)bias[n];
      int mb = m0 + wm + i * 16 + quad * 4;
      if (n < 2048) {
#pragma unroll
        for (int r = 0; r < 4; r++)
          QK[(size_t)(mb + r) * 2048 + n] = (bf16)(acc[i][j][r] + bv);
      } else {
        bf16x4 pk;
#pragma unroll
        for (int r = 0; r < 4; r++) pk[r] = (bf16)(acc[i][j][r] + bv);
        *(bf16x4*)&Vt[(size_t)(n - 2048) * TOKENS + mb] = pk;
      }
    }
}

// ------------------------------------------------------------------
// Flash attention: 256 threads (4 waves), 64 queries/block, 64-key tiles.
// K from QK buffer (natural layout); V from Vt (pre-transposed [d][token]).
// Per-wave P buffer -> no extra barriers for the C->A layout round-trip.
// Staging: 256 threads x 2 passes x 8 bf16 = full 64x64 tile (round-4 bug
// was half-coverage -> uninitialized LDS -> NaN).
// ------------------------------------------------------------------
__global__ __launch_bounds__(256) void attn_kernel(const bf16* __restrict__ QK,
                                                   const bf16* __restrict__ Vt,
                                                   bf16* __restrict__ O) {
  __shared__ alignas(16) bf16 Ks[64][72];       // [key][d]   pad->2-way only
  __shared__ alignas(16) bf16 Vs[64][72];       // [d][key]
  __shared__ alignas(16) bf16 Ps[4][16][72];    // per-wave P [qrow][key]
  int b = blockIdx.z, h = blockIdx.y, q0 = blockIdx.x * 64;
  int t = threadIdx.x, wave = t >> 6, lane = t & 63, quad = lane >> 4, l16 = lane & 15;

  const bf16* Qg = QK;
  const bf16* Kg = QK + 1024;

  int qrow = b * TSEQ + q0 + wave * 16 + l16;
  bf16x8 aq[2];
  aq[0] = *(const bf16x8*)&Qg[(size_t)qrow * 2048 + h * 64 + quad * 8];
  aq[1] = *(const bf16x8*)&Qg[(size_t)qrow * 2048 + h * 64 + 32 + quad * 8];

  float m_i[4], l_i[4];
  f32x4 accO[4] = {};
#pragma unroll
  for (int r = 0; r < 4; r++) { m_i[r] = -1e30f; l_i[r] = 0.f; }
  const float scale = 0.125f;

  int srow2 = t >> 3;        // 0..31  (two passes: rows srow2, srow2+32)
  int sc8 = t & 7;           // 0..7   (8 chunks of 8 bf16 = full 64 cols)
  for (int t0 = 0; t0 < TSEQ; t0 += 64) {
#pragma unroll
    for (int hp = 0; hp < 2; hp++) {
      int row = srow2 + hp * 32;
      *(bf16x8*)&Ks[row][sc8 * 8] =
          *(const bf16x8*)&Kg[(size_t)(b * TSEQ + t0 + row) * 2048 + h * 64 + sc8 * 8];
      *(bf16x8*)&Vs[row][sc8 * 8] =
          *(const bf16x8*)&Vt[(size_t)(h * 64 + row) * TOKENS + b * TSEQ + t0 + sc8 * 8];
    }
    __syncthreads();

    // S = Q K^T : 4 key subtiles of 16
    f32x4 S[4];
#pragma unroll
    for (int c = 0; c < 4; c++) {
      bf16x8 kb0 = *(const bf16x8*)&Ks[c * 16 + l16][quad * 8];
      bf16x8 kb1 = *(const bf16x8*)&Ks[c * 16 + l16][32 + quad * 8];
      f32x4 s = {};
      s = __builtin_amdgcn_mfma_f32_16x16x32_bf16(aq[0], kb0, s, 0, 0, 0);
      s = __builtin_amdgcn_mfma_f32_16x16x32_bf16(aq[1], kb1, s, 0, 0, 0);
      S[c] = s;
    }

    // online softmax per row r (reduction over c and 16 lanes)
    float alpha[4];
#pragma unroll
    for (int r = 0; r < 4; r++) {
      float sc0 = S[0][r] * scale, sc1 = S[1][r] * scale;
      float sc2 = S[2][r] * scale, sc3 = S[3][r] * scale;
      float mx = fmaxf(fmaxf(sc0, sc1), fmaxf(sc2, sc3));
#pragma unroll
      for (int off = 1; off < 16; off <<= 1) mx = fmaxf(mx, __shfl_xor(mx, off));
      float mnew = fmaxf(m_i[r], mx);
      alpha[r] = __expf(m_i[r] - mnew);
      m_i[r] = mnew;
      float p0 = __expf(sc0 - mnew), p1 = __expf(sc1 - mnew);
      float p2 = __expf(sc2 - mnew), p3 = __expf(sc3 - mnew);
      float rs = (p0 + p1) + (p2 + p3);
#pragma unroll
      for (int off = 1; off < 16; off <<= 1) rs += __shfl_xor(rs, off);
      l_i[r] = l_i[r] * alpha[r] + rs;
      int pr = quad * 4 + r;
      Ps[wave][pr][l16]      = (bf16)p0;
      Ps[wave][pr][16 + l16] = (bf16)p1;
      Ps[wave][pr][32 + l16] = (bf16)p2;
      Ps[wave][pr][48 + l16] = (bf16)p3;
    }

    // PV (per-wave P; ds ops in-order within a wave, compiler inserts waits)
    bf16x8 pa0 = *(const bf16x8*)&Ps[wave][l16][quad * 8];
    bf16x8 pa1 = *(const bf16x8*)&Ps[wave][l16][32 + quad * 8];
#pragma unroll
    for (int ds = 0; ds < 4; ds++) {
      bf16x8 vb0 = *(const bf16x8*)&Vs[ds * 16 + l16][quad * 8];
      bf16x8 vb1 = *(const bf16x8*)&Vs[ds * 16 + l16][32 + quad * 8];
#pragma unroll
      for (int r = 0; r < 4; r++) accO[ds][r] *= alpha[r];
      accO[ds] = __builtin_amdgcn_mfma_f32_16x16x32_bf16(pa0, vb0, accO[ds], 0, 0, 0);
      accO[ds] = __builtin_amdgcn_mfma_f32_16x16x32_bf16(pa1, vb1, accO[ds], 0, 0, 0);
    }
    __syncthreads();
  }

#pragma unroll
  for (int ds = 0; ds < 4; ds++)
#pragma unroll
    for (int r = 0; r < 4; r++) {
      float v = accO[ds][r] / fmaxf(l_i[r], 1e-30f);
      O[(size_t)(b * TSEQ + q0 + wave * 16 + quad * 4 + r) * CDIM + h * 64 + ds * 16 + l16] = (bf16)v;
    }
}

// ------------------------------------------------------------------
extern "C" void kernel_launch(void* const* d_in, const int* in_sizes, int n_in,
                              void* d_out, int out_size, void* d_ws, size_t ws_size,
                              hipStream_t stream) {
  char* ws = (char*)d_ws;
  const size_t MB = 1024 * 1024;
  const size_t KB = 1024;

  int* flags = (int*)ws;
  bf16* vec_c = (bf16*)(ws + 4 * KB);
  bf16* ln1g_c = vec_c + 0 * 8192;
  bf16* ln1b_c = vec_c + 1 * 8192;
  bf16* ln2g_c = vec_c + 2 * 8192;
  bf16* ln2b_c = vec_c + 3 * 8192;
  bf16* bqkv_c = vec_c + 4 * 8192;            // [3072]: bq | bk | bv
  bf16* bo_c   = vec_c + 6 * 8192;
  bf16* b1_c   = vec_c + 7 * 8192;            // [4096] fits
  bf16* b2_c   = vec_c + 8 * 8192;

  bf16*  x_c    = (bf16*)(ws + 1 * MB);       // 1-9
  bf16*  WqkvT  = (bf16*)(ws + 9 * MB);       // [3072][1024]  9-15
  bf16*  WoT    = (bf16*)(ws + 15 * MB);      // 15-17
  bf16*  W1T    = (bf16*)(ws + 17 * MB);      // 17-25
  bf16*  W2T    = (bf16*)(ws + 25 * MB);      // 25-33
  bf16*  Wq_c   = (bf16*)(ws + 33 * MB);      // raw converts (dead after transpose)
  bf16*  Wk_c   = (bf16*)(ws + 35 * MB);
  bf16*  Wv_c   = (bf16*)(ws + 37 * MB);
  bf16*  Wo_c   = (bf16*)(ws + 39 * MB);
  bf16*  W1_c   = (bf16*)(ws + 41 * MB);      // 41-49
  bf16*  W2_c   = (bf16*)(ws + 49 * MB);      // 49-57
  bf16*  xn     = (bf16*)(ws + 57 * MB);      // 57-65 (dead after Wo GEMM)
  bf16*  QKbuf  = (bf16*)(ws + 65 * MB);      // [4096][2048] 65-81 (dead after attn)
  bf16*  Vtbuf  = (bf16*)(ws + 81 * MB);      // [1024][4096] 81-89 (dead after attn)
  bf16*  ab     = (bf16*)(ws + 89 * MB);      // 89-97 (dead after Wo GEMM)
  float* xmid32 = (float*)(ws + 65 * MB);     // 65-81 fp32, reuses dead QKbuf
  bf16*  h2     = (bf16*)(ws + 81 * MB);      // reuses dead Vtbuf
  bf16*  f1     = (bf16*)(ws + 33 * MB);      // [4096][4096] 33-65, reuses dead converts+xn

  // ---- detect + convert inputs ----
  const int din_idx[NBUF] = {0, 2, 3, 4, 5, 6, 7, 8, 9, 10, 11, 12, 13, 14, 15, 16, 17};
  DetectArgs da;
  for (int i = 0; i < NBUF; i++) { da.p[i] = d_in[din_idx[i]]; da.n[i] = in_sizes[din_idx[i]]; }
  detect_kernel<<<NBUF, 256, 0, stream>>>(da, flags);

  bf16* dsts[NBUF] = {x_c, ln1g_c, ln1b_c, ln2g_c, ln2b_c,
                      Wq_c, bqkv_c, Wk_c, bqkv_c + 1024, Wv_c, bqkv_c + 2048,
                      Wo_c, bo_c, W1_c, b1_c, W2_c, b2_c};
  for (int i = 0; i < NBUF; i++) {
    int cnt = in_sizes[din_idx[i]];
    convert_to_bf16<<<(cnt + 255) / 256, 256, 0, stream>>>(d_in[din_idx[i]], dsts[i], cnt, flags + i);
  }

  // ---- transpose weights (Wq/Wk/Wv into concatenated WqkvT) ----
  dim3 tb(64, 4);
  transpose_bf16<<<dim3(16, 16), tb, 0, stream>>>(Wq_c, WqkvT, 1024, 1024);
  transpose_bf16<<<dim3(16, 16), tb, 0, stream>>>(Wk_c, WqkvT + 1024 * 1024, 1024, 1024);
  transpose_bf16<<<dim3(16, 16), tb, 0, stream>>>(Wv_c, WqkvT + 2 * 1024 * 1024, 1024, 1024);
  transpose_bf16<<<dim3(16, 16), tb, 0, stream>>>(Wo_c, WoT, 1024, 1024);
  transpose_bf16<<<dim3(64, 16), tb, 0, stream>>>(W1_c, W1T, 1024, 4096);
  transpose_bf16<<<dim3(16, 64), tb, 0, stream>>>(W2_c, W2T, 4096, 1024);

  // ---- pipeline ----
  ln_kernel<bf16><<<TOKENS, 256, 0, stream>>>(x_c, ln1g_c, ln1b_c, xn);

  gemm_qkv<<<dim3(24, 32), 256, 0, stream>>>(xn, WqkvT, bqkv_c, QKbuf, Vtbuf);

  attn_kernel<<<dim3(TSEQ / 64, NHEADS, 2), 256, 0, stream>>>(QKbuf, Vtbuf, ab);

  gemm128<64, 128, EPI_RES, float, bf16><<<dim3(8, 64), 256, 0, stream>>>(
      ab, WoT, bo_c, xn, xmid32, 1024, 1024);

  ln_kernel<float><<<TOKENS, 256, 0, stream>>>(xmid32, ln2g_c, ln2b_c, h2);

  gemm128<128, 128, EPI_GELU, bf16, bf16><<<dim3(32, 32), 256, 0, stream>>>(
      h2, W1T, b1_c, (const bf16*)nullptr, f1, 4096, 1024);

  gemm128<64, 128, EPI_RES, float, float><<<dim3(8, 64), 256, 0, stream>>>(
      f1, W2T, b2_c, xmid32, (float*)d_out, 1024, 4096);
}

// Round 6
// 505.227 us; speedup vs baseline: 1.4249x; 1.0638x over previous
//
#include <hip/hip_runtime.h>
#include <cstdint>
#include <cstddef>

typedef __bf16 bf16;
typedef __bf16 bf16x8 __attribute__((ext_vector_type(8)));
typedef __bf16 bf16x4 __attribute__((ext_vector_type(4)));
typedef float f32x4 __attribute__((ext_vector_type(4)));

#define TOKENS 4096   // B*T
#define TSEQ   2048
#define NHEADS 16
#define HDIM   64
#define CDIM   1024

// ---- async global->LDS, 16B per lane ----
typedef __attribute__((address_space(3))) unsigned int lds_uint;
typedef __attribute__((address_space(1))) const unsigned int g_uint;
__device__ __forceinline__ void glds16(const bf16* g, bf16* l) {
  __builtin_amdgcn_global_load_lds((g_uint*)g, (lds_uint*)l, 16, 0, 0);
}

// ------------------------------------------------------------------
// Input dtype detection (insurance; fp32 -> flag 0). See round-2 note.
// ------------------------------------------------------------------
#define NBUF 17
struct DetectArgs { const void* p[NBUF]; int n[NBUF]; };

__global__ __launch_bounds__(256) void detect_kernel(DetectArgs a, int* __restrict__ flags) {
  __shared__ int s_nz, s_bl;
  if (threadIdx.x == 0) { s_nz = 0; s_bl = 0; }
  __syncthreads();
  int i = blockIdx.x;
  const unsigned int* w = (const unsigned int*)a.p[i];
  int nwords = a.n[i] / 2; if (nwords > 2048) nwords = 2048;
  int nz = 0, bl = 0;
  for (int j = threadIdx.x; j < nwords; j += 256) {
    unsigned int v = w[j];
    if (v != 0u) {
      nz++;
      unsigned int e = (v >> 7) & 0xFFu;
      if (e >= 100u && e <= 140u) bl++;
    }
  }
  atomicAdd(&s_nz, nz);
  atomicAdd(&s_bl, bl);
  __syncthreads();
  if (threadIdx.x == 0) flags[i] = (2 * s_bl >= s_nz) ? 1 : 0;
}

__global__ __launch_bounds__(256) void convert_to_bf16(const void* __restrict__ in,
                                                       bf16* __restrict__ out,
                                                       int count, const int* __restrict__ flag) {
  int i = blockIdx.x * 256 + threadIdx.x;
  if (i >= count) return;
  if (*flag) out[i] = ((const bf16*)in)[i];
  else       out[i] = (bf16)(((const float*)in)[i]);
}

// ------------------------------------------------------------------
// Weight transpose with fused dtype convert: in[K][N] -> out[N][K]
// ------------------------------------------------------------------
__global__ __launch_bounds__(256) void transpose_any(const void* __restrict__ in,
                                                     bf16* __restrict__ out,
                                                     int K, int N,
                                                     const int* __restrict__ flag) {
  __shared__ bf16 tile[64][65];
  int kb = blockIdx.y * 64, nb = blockIdx.x * 64;
  int tx = threadIdx.x, ty = threadIdx.y;   // blockDim (64,4)
  bool isb = (*flag != 0);
  for (int i = ty; i < 64; i += 4) {
    size_t idx = (size_t)(kb + i) * N + nb + tx;
    tile[i][tx] = isb ? ((const bf16*)in)[idx] : (bf16)(((const float*)in)[idx]);
  }
  __syncthreads();
  for (int i = ty; i < 64; i += 4)
    out[(size_t)(nb + i) * K + kb + tx] = tile[tx][i];
}

// ------------------------------------------------------------------
// LayerNorm rows of 1024, fp32 math. ln_any: runtime dtype (for x).
// ------------------------------------------------------------------
__device__ __forceinline__ void ln_body(const float (&v)[4], float s, float s2,
                                        const bf16* g, const bf16* b, bf16* yr, int tid) {
#pragma unroll
  for (int off = 32; off; off >>= 1) {
    s  += __shfl_down(s, off);
    s2 += __shfl_down(s2, off);
  }
  __shared__ float red[8];
  int w = tid >> 6;
  if ((tid & 63) == 0) { red[w] = s; red[4 + w] = s2; }
  __syncthreads();
  if (tid == 0) {
    red[0] = red[0] + red[1] + red[2] + red[3];
    red[4] = red[4] + red[5] + red[6] + red[7];
  }
  __syncthreads();
  float mu  = red[0] * (1.0f / CDIM);
  float var = fmaxf(red[4] * (1.0f / CDIM) - mu * mu, 0.f);
  float rstd = rsqrtf(var + 1e-5f);
#pragma unroll
  for (int i = 0; i < 4; i++) {
    int c = tid * 4 + i;
    yr[c] = (bf16)((v[i] - mu) * rstd * (float)g[c] + (float)b[c]);
  }
}

__global__ __launch_bounds__(256) void ln_any(const void* __restrict__ x,
                                              const int* __restrict__ flag,
                                              const bf16* __restrict__ g,
                                              const bf16* __restrict__ b,
                                              bf16* __restrict__ y) {
  int row = blockIdx.x, tid = threadIdx.x;
  bool isb = (*flag != 0);
  float v[4]; float s = 0.f, s2 = 0.f;
#pragma unroll
  for (int i = 0; i < 4; i++) {
    size_t idx = (size_t)row * CDIM + tid * 4 + i;
    float f = isb ? (float)((const bf16*)x)[idx] : ((const float*)x)[idx];
    v[i] = f; s += f; s2 += f * f;
  }
  ln_body(v, s, s2, g, b, y + (size_t)row * CDIM, tid);
}

__global__ __launch_bounds__(256) void ln_f32(const float* __restrict__ x,
                                              const bf16* __restrict__ g,
                                              const bf16* __restrict__ b,
                                              bf16* __restrict__ y) {
  int row = blockIdx.x, tid = threadIdx.x;
  float v[4]; float s = 0.f, s2 = 0.f;
#pragma unroll
  for (int i = 0; i < 4; i++) {
    float f = x[(size_t)row * CDIM + tid * 4 + i];
    v[i] = f; s += f; s2 += f * f;
  }
  ln_body(v, s, s2, g, b, y + (size_t)row * CDIM, tid);
}

// ------------------------------------------------------------------
// m97-style GEMM core (unchanged from round 5)
// ------------------------------------------------------------------
template <int BM, int BN>
__device__ __forceinline__ void gemm_core(const bf16* __restrict__ A,
                                          const bf16* __restrict__ Bt,
                                          int K, int m0, int n0,
                                          bf16* As, bf16* Bs,
                                          f32x4 (&acc)[BM / 32][BN / 32]) {
  constexpr int SI = BM / 32, SJ = BN / 32;
  int t = threadIdx.x;
  int wave = t >> 6, lane = t & 63, quad = lane >> 4, l16 = lane & 15;
  int wm = (wave & 1) * (BM / 2), wn = (wave >> 1) * (BN / 2);
  int srow = t >> 2, sc = t & 3;
  int swz = (srow >> 1) & 3;
  const bf16* ga[BM / 64];
  const bf16* gb[BN / 64];
#pragma unroll
  for (int h = 0; h < BM / 64; h++)
    ga[h] = A + (size_t)(m0 + h * 64 + srow) * K + (sc ^ swz) * 8;
#pragma unroll
  for (int h = 0; h < BN / 64; h++)
    gb[h] = Bt + (size_t)(n0 + h * 64 + srow) * K + (sc ^ swz) * 8;

  for (int k0 = 0; k0 < K; k0 += 32) {
#pragma unroll
    for (int h = 0; h < BM / 64; h++)
      glds16(ga[h] + k0, As + h * 2048 + srow * 32 + sc * 8);
#pragma unroll
    for (int h = 0; h < BN / 64; h++)
      glds16(gb[h] + k0, Bs + h * 2048 + srow * 32 + sc * 8);
    __syncthreads();

    bf16x8 af[SI], bfr[SJ];
#pragma unroll
    for (int i = 0; i < SI; i++) {
      int m = wm + i * 16 + l16;
      af[i] = *(const bf16x8*)&As[m * 32 + ((quad ^ ((m >> 1) & 3)) * 8)];
    }
#pragma unroll
    for (int j = 0; j < SJ; j++) {
      int n = wn + j * 16 + l16;
      bfr[j] = *(const bf16x8*)&Bs[n * 32 + ((quad ^ ((n >> 1) & 3)) * 8)];
    }
#pragma unroll
    for (int i = 0; i < SI; i++)
#pragma unroll
      for (int j = 0; j < SJ; j++)
        acc[i][j] = __builtin_amdgcn_mfma_f32_16x16x32_bf16(af[i], bfr[j], acc[i][j], 0, 0, 0);
    __syncthreads();
  }
}

#define EPI_NONE 0
#define EPI_RES  1
#define EPI_GELU 2

template <int BM, int BN, int EPI, typename OutT, typename ResT>
__global__ __launch_bounds__(256) void gemm128(const bf16* __restrict__ A,
                                               const bf16* __restrict__ Bt,
                                               const bf16* __restrict__ bias,
                                               const ResT* __restrict__ res,
                                               OutT* __restrict__ C,
                                               int N, int K) {
  __shared__ alignas(16) bf16 As[BM * 32];
  __shared__ alignas(16) bf16 Bs[BN * 32];
  int m0 = blockIdx.y * BM, n0 = blockIdx.x * BN;
  f32x4 acc[BM / 32][BN / 32] = {};
  gemm_core<BM, BN>(A, Bt, K, m0, n0, As, Bs, acc);

  int t = threadIdx.x, wave = t >> 6, lane = t & 63, quad = lane >> 4, l16 = lane & 15;
  int wm = (wave & 1) * (BM / 2), wn = (wave >> 1) * (BN / 2);
#pragma unroll
  for (int i = 0; i < BM / 32; i++)
#pragma unroll
    for (int j = 0; j < BN / 32; j++) {
      int n = n0 + wn + j * 16 + l16;
      float bv = (float)bias[n];
#pragma unroll
      for (int r = 0; r < 4; r++) {
        int m = m0 + wm + i * 16 + quad * 4 + r;
        float v = acc[i][j][r] + bv;
        if (EPI == EPI_GELU)      v = 0.5f * v * (1.0f + erff(v * 0.70710678118654752f));
        else if (EPI == EPI_RES)  v += (float)res[(size_t)m * N + n];
        C[(size_t)m * N + n] = (OutT)v;
      }
    }
}

// QKV GEMM. Q cols (n<1024) pre-scaled by 1/8 (exact, pow2) so attention
// needs no score scaling. V cols (n>=2048) written transposed [d][token].
__global__ __launch_bounds__(256) void gemm_qkv(const bf16* __restrict__ A,
                                                const bf16* __restrict__ Bt,
                                                const bf16* __restrict__ bias,
                                                bf16* __restrict__ QK,
                                                bf16* __restrict__ Vt) {
  __shared__ alignas(16) bf16 As[128 * 32];
  __shared__ alignas(16) bf16 Bs[128 * 32];
  int m0 = blockIdx.y * 128, n0 = blockIdx.x * 128;
  f32x4 acc[4][4] = {};
  gemm_core<128, 128>(A, Bt, 1024, m0, n0, As, Bs, acc);

  int t = threadIdx.x, wave = t >> 6, lane = t & 63, quad = lane >> 4, l16 = lane & 15;
  int wm = (wave & 1) * 64, wn = (wave >> 1) * 64;
#pragma unroll
  for (int i = 0; i < 4; i++)
#pragma unroll
    for (int j = 0; j < 4; j++) {
      int n = n0 + wn + j * 16 + l16;
      float bv = (float)bias[n];
      int mb = m0 + wm + i * 16 + quad * 4;
      if (n < 1024) {
#pragma unroll
        for (int r = 0; r < 4; r++)
          QK[(size_t)(mb + r) * 2048 + n] = (bf16)((acc[i][j][r] + bv) * 0.125f);
      } else if (n < 2048) {
#pragma unroll
        for (int r = 0; r < 4; r++)
          QK[(size_t)(mb + r) * 2048 + n] = (bf16)(acc[i][j][r] + bv);
      } else {
        bf16x4 pk;
#pragma unroll
        for (int r = 0; r < 4; r++) pk[r] = (bf16)(acc[i][j][r] + bv);
        *(bf16x4*)&Vt[(size_t)(n - 2048) * TOKENS + mb] = pk;
      }
    }
}

// ------------------------------------------------------------------
// Flash attention, shuffle-free softmax.
// softmax is shift-invariant: O/l identical without max subtraction;
// scores ~N(0,2) (Q pre-scaled), clamp at 60 guards overflow (e^60 ok
// in f32/bf16). Row sums l come from MFMA with an all-ones B operand.
// K/V staged via global_load_lds (XOR-chunk swizzle), double-buffered,
// one barrier per 64-key tile.
// ------------------------------------------------------------------
__global__ __launch_bounds__(256) void attn_kernel(const bf16* __restrict__ QK,
                                                   const bf16* __restrict__ Vt,
                                                   bf16* __restrict__ O) {
  __shared__ alignas(16) bf16 Ks[2][4096];      // [key][d] 64x64, swizzled
  __shared__ alignas(16) bf16 Vs[2][4096];      // [d][key] 64x64, swizzled
  __shared__ alignas(16) bf16 Ps[4][16][72];    // per-wave P [qrow][key]
  int b = blockIdx.z, h = blockIdx.y, q0 = blockIdx.x * 64;
  int t = threadIdx.x, wave = t >> 6, lane = t & 63, quad = lane >> 4, l16 = lane & 15;

  const bf16* Qg = QK;
  const bf16* Kg = QK + 1024;
  const size_t bT = (size_t)b * TSEQ;
  const int h64 = h * 64;

  // staging source mapping (glds16 dest is wave_base + lane*16):
  // lane -> row (8w + lane>>3), phys chunk lane&7 holds logical chunk (lane&7)^(row&7)
  int srow = lane >> 3;
  int schunk = (lane & 7) ^ srow;

  bf16x8 aq0, aq1;
  {
    size_t qrow = bT + q0 + wave * 16 + l16;
    aq0 = *(const bf16x8*)&Qg[qrow * 2048 + h64 + quad * 8];
    aq1 = *(const bf16x8*)&Qg[qrow * 2048 + h64 + 32 + quad * 8];
  }

  f32x4 accO[4] = {};
  f32x4 accL = {};

  auto stage = [&](int tile, int buf) {
#pragma unroll
    for (int hp = 0; hp < 2; hp++) {
      int row = hp * 32 + wave * 8 + srow;
      glds16(&Kg[(bT + tile * 64 + row) * 2048 + h64 + schunk * 8],
             &Ks[buf][hp * 2048 + wave * 512 + lane * 8]);
      glds16(&Vt[(size_t)(h64 + row) * TOKENS + bT + tile * 64 + schunk * 8],
             &Vs[buf][hp * 2048 + wave * 512 + lane * 8]);
    }
  };

  const bf16 one = (bf16)1.0f;
  const bf16x8 onesv = {one, one, one, one, one, one, one, one};
  int sw = l16 & 7;

  stage(0, 0);
  __syncthreads();

  for (int it = 0; it < TSEQ / 64; it++) {
    int cur = it & 1;
    if (it + 1 < TSEQ / 64) stage(it + 1, cur ^ 1);

    const bf16* KsC = &Ks[cur][0];
    const bf16* VsC = &Vs[cur][0];

    // S = Q K^T (scores already scaled via Q)
    f32x4 S[4];
#pragma unroll
    for (int c = 0; c < 4; c++) {
      int row = c * 16 + l16;
      bf16x8 kb0 = *(const bf16x8*)&KsC[row * 64 + ((quad ^ sw) * 8)];
      bf16x8 kb1 = *(const bf16x8*)&KsC[row * 64 + (((quad + 4) ^ sw) * 8)];
      f32x4 s = {};
      s = __builtin_amdgcn_mfma_f32_16x16x32_bf16(aq0, kb0, s, 0, 0, 0);
      s = __builtin_amdgcn_mfma_f32_16x16x32_bf16(aq1, kb1, s, 0, 0, 0);
      S[c] = s;
    }

    // P = exp(S) (no shift), store to per-wave LDS in A-layout rows
#pragma unroll
    for (int c = 0; c < 4; c++)
#pragma unroll
      for (int r = 0; r < 4; r++)
        Ps[wave][quad * 4 + r][c * 16 + l16] = (bf16)__expf(fminf(S[c][r], 60.f));

    // PV + row-sum via ones-column
    bf16x8 pa0 = *(const bf16x8*)&Ps[wave][l16][quad * 8];
    bf16x8 pa1 = *(const bf16x8*)&Ps[wave][l16][32 + quad * 8];
#pragma unroll
    for (int ds = 0; ds < 4; ds++) {
      int row = ds * 16 + l16;
      bf16x8 vb0 = *(const bf16x8*)&VsC[row * 64 + ((quad ^ sw) * 8)];
      bf16x8 vb1 = *(const bf16x8*)&VsC[row * 64 + (((quad + 4) ^ sw) * 8)];
      accO[ds] = __builtin_amdgcn_mfma_f32_16x16x32_bf16(pa0, vb0, accO[ds], 0, 0, 0);
      accO[ds] = __builtin_amdgcn_mfma_f32_16x16x32_bf16(pa1, vb1, accO[ds], 0, 0, 0);
    }
    accL = __builtin_amdgcn_mfma_f32_16x16x32_bf16(pa0, onesv, accL, 0, 0, 0);
    accL = __builtin_amdgcn_mfma_f32_16x16x32_bf16(pa1, onesv, accL, 0, 0, 0);

    __syncthreads();
  }

#pragma unroll
  for (int ds = 0; ds < 4; ds++)
#pragma unroll
    for (int r = 0; r < 4; r++) {
      float v = accO[ds][r] / fmaxf(accL[r], 1e-30f);
      O[(bT + q0 + wave * 16 + quad * 4 + r) * CDIM + h64 + ds * 16 + l16] = (bf16)v;
    }
}

// ------------------------------------------------------------------
extern "C" void kernel_launch(void* const* d_in, const int* in_sizes, int n_in,
                              void* d_out, int out_size, void* d_ws, size_t ws_size,
                              hipStream_t stream) {
  char* ws = (char*)d_ws;
  const size_t MB = 1024 * 1024;
  const size_t KB = 1024;

  int* flags = (int*)ws;
  bf16* vec_c = (bf16*)(ws + 4 * KB);
  bf16* ln1g_c = vec_c + 0 * 8192;
  bf16* ln1b_c = vec_c + 1 * 8192;
  bf16* ln2g_c = vec_c + 2 * 8192;
  bf16* ln2b_c = vec_c + 3 * 8192;
  bf16* bqkv_c = vec_c + 4 * 8192;            // [3072]: bq | bk | bv
  bf16* bo_c   = vec_c + 6 * 8192;
  bf16* b1_c   = vec_c + 7 * 8192;
  bf16* b2_c   = vec_c + 8 * 8192;

  bf16*  WqkvT  = (bf16*)(ws + 1 * MB);       // [3072][1024]  1-7
  bf16*  WoT    = (bf16*)(ws + 7 * MB);       // 7-9
  bf16*  W1T    = (bf16*)(ws + 9 * MB);       // 9-17
  bf16*  W2T    = (bf16*)(ws + 17 * MB);      // 17-25
  bf16*  xn     = (bf16*)(ws + 25 * MB);      // 25-33  (live until Wo GEMM)
  bf16*  QKbuf  = (bf16*)(ws + 33 * MB);      // [4096][2048] 33-49 (dead after attn)
  bf16*  Vtbuf  = (bf16*)(ws + 49 * MB);      // [1024][4096] 49-57 (dead after attn)
  bf16*  ab     = (bf16*)(ws + 57 * MB);      // 57-65 (dead after Wo GEMM)
  float* xmid32 = (float*)(ws + 65 * MB);     // 65-81 fp32
  bf16*  h2     = (bf16*)(ws + 81 * MB);      // 81-89
  bf16*  f1     = (bf16*)(ws + 33 * MB);      // [4096][4096] 33-65 (reuses dead bufs)

  // ---- detect dtypes ----
  // flag idx: 0 x,1 ln1g,2 ln1b,3 ln2g,4 ln2b,5 Wq,6 bq,7 Wk,8 bk,9 Wv,10 bv,
  //           11 Wo,12 bo,13 W1,14 b1,15 W2,16 b2
  const int din_idx[NBUF] = {0, 2, 3, 4, 5, 6, 7, 8, 9, 10, 11, 12, 13, 14, 15, 16, 17};
  DetectArgs da;
  for (int i = 0; i < NBUF; i++) { da.p[i] = d_in[din_idx[i]]; da.n[i] = in_sizes[din_idx[i]]; }
  detect_kernel<<<NBUF, 256, 0, stream>>>(da, flags);

  // ---- convert small vectors only (weights/x convert fused downstream) ----
  const int vec_flag[10] = {1, 2, 3, 4, 6, 8, 10, 12, 14, 16};
  bf16* vec_dst[10] = {ln1g_c, ln1b_c, ln2g_c, ln2b_c,
                       bqkv_c, bqkv_c + 1024, bqkv_c + 2048, bo_c, b1_c, b2_c};
  for (int i = 0; i < 10; i++) {
    int di = din_idx[vec_flag[i]];
    int cnt = in_sizes[di];
    convert_to_bf16<<<(cnt + 255) / 256, 256, 0, stream>>>(d_in[di], vec_dst[i], cnt, flags + vec_flag[i]);
  }

  // ---- transpose weights (convert fused) ----
  dim3 tb(64, 4);
  transpose_any<<<dim3(16, 16), tb, 0, stream>>>(d_in[6],  WqkvT,                 1024, 1024, flags + 5);
  transpose_any<<<dim3(16, 16), tb, 0, stream>>>(d_in[8],  WqkvT + 1024 * 1024,   1024, 1024, flags + 7);
  transpose_any<<<dim3(16, 16), tb, 0, stream>>>(d_in[10], WqkvT + 2 * 1024 * 1024, 1024, 1024, flags + 9);
  transpose_any<<<dim3(16, 16), tb, 0, stream>>>(d_in[12], WoT, 1024, 1024, flags + 11);
  transpose_any<<<dim3(64, 16), tb, 0, stream>>>(d_in[14], W1T, 1024, 4096, flags + 13);
  transpose_any<<<dim3(16, 64), tb, 0, stream>>>(d_in[16], W2T, 4096, 1024, flags + 15);

  // ---- pipeline ----
  ln_any<<<TOKENS, 256, 0, stream>>>(d_in[0], flags + 0, ln1g_c, ln1b_c, xn);

  gemm_qkv<<<dim3(24, 32), 256, 0, stream>>>(xn, WqkvT, bqkv_c, QKbuf, Vtbuf);

  attn_kernel<<<dim3(TSEQ / 64, NHEADS, 2), 256, 0, stream>>>(QKbuf, Vtbuf, ab);

  gemm128<64, 128, EPI_RES, float, bf16><<<dim3(8, 64), 256, 0, stream>>>(
      ab, WoT, bo_c, xn, xmid32, 1024, 1024);

  ln_f32<<<TOKENS, 256, 0, stream>>>(xmid32, ln2g_c, ln2b_c, h2);

  gemm128<128, 128, EPI_GELU, bf16, bf16><<<dim3(32, 32), 256, 0, stream>>>(
      h2, W1T, b1_c, (const bf16*)nullptr, f1, 4096, 1024);

  gemm128<64, 128, EPI_RES, float, float><<<dim3(8, 64), 256, 0, stream>>>(
      f1, W2T, b2_c, xmid32, (float*)d_out, 1024, 4096);
}

// Round 7
// 453.722 us; speedup vs baseline: 1.5866x; 1.1135x over previous
//
#include <hip/hip_runtime.h>
#include <cstdint>
#include <cstddef>

typedef __bf16 bf16;
typedef __bf16 bf16x8 __attribute__((ext_vector_type(8)));
typedef __bf16 bf16x4 __attribute__((ext_vector_type(4)));
typedef float f32x4 __attribute__((ext_vector_type(4)));

#define TOKENS 4096   // B*T
#define TSEQ   2048
#define NHEADS 16
#define HDIM   64
#define CDIM   1024

// ---- async global->LDS, 16B per lane ----
typedef __attribute__((address_space(3))) unsigned int lds_uint;
typedef __attribute__((address_space(1))) const unsigned int g_uint;
__device__ __forceinline__ void glds16(const bf16* g, bf16* l) {
  __builtin_amdgcn_global_load_lds((g_uint*)g, (lds_uint*)l, 16, 0, 0);
}

// ------------------------------------------------------------------
// Input dtype detection (insurance; fp32 -> flag 0). See round-2 note.
// ------------------------------------------------------------------
#define NBUF 17
struct DetectArgs { const void* p[NBUF]; int n[NBUF]; };

__global__ __launch_bounds__(256) void detect_kernel(DetectArgs a, int* __restrict__ flags) {
  __shared__ int s_nz, s_bl;
  if (threadIdx.x == 0) { s_nz = 0; s_bl = 0; }
  __syncthreads();
  int i = blockIdx.x;
  const unsigned int* w = (const unsigned int*)a.p[i];
  int nwords = a.n[i] / 2; if (nwords > 2048) nwords = 2048;
  int nz = 0, bl = 0;
  for (int j = threadIdx.x; j < nwords; j += 256) {
    unsigned int v = w[j];
    if (v != 0u) {
      nz++;
      unsigned int e = (v >> 7) & 0xFFu;
      if (e >= 100u && e <= 140u) bl++;
    }
  }
  atomicAdd(&s_nz, nz);
  atomicAdd(&s_bl, bl);
  __syncthreads();
  if (threadIdx.x == 0) flags[i] = (2 * s_bl >= s_nz) ? 1 : 0;
}

// ---- all 10 small vectors converted in one launch ----
struct VecCvt { const void* p[10]; bf16* d[10]; int n[10]; int fi[10]; };
__global__ __launch_bounds__(256) void convert_vecs(VecCvt a, const int* __restrict__ flags) {
  int i = blockIdx.x;
  bool isb = flags[a.fi[i]] != 0;
  const void* in = a.p[i]; bf16* out = a.d[i]; int n = a.n[i];
  for (int j = threadIdx.x; j < n; j += 256)
    out[j] = isb ? ((const bf16*)in)[j] : (bf16)(((const float*)in)[j]);
}

// ------------------------------------------------------------------
// Weight transpose with fused dtype convert: in[K][N] -> out[N][K]
// ------------------------------------------------------------------
__global__ __launch_bounds__(256) void transpose_any(const void* __restrict__ in,
                                                     bf16* __restrict__ out,
                                                     int K, int N,
                                                     const int* __restrict__ flag) {
  __shared__ bf16 tile[64][65];
  int kb = blockIdx.y * 64, nb = blockIdx.x * 64;
  int tx = threadIdx.x, ty = threadIdx.y;   // blockDim (64,4)
  bool isb = (*flag != 0);
  for (int i = ty; i < 64; i += 4) {
    size_t idx = (size_t)(kb + i) * N + nb + tx;
    tile[i][tx] = isb ? ((const bf16*)in)[idx] : (bf16)(((const float*)in)[idx]);
  }
  __syncthreads();
  for (int i = ty; i < 64; i += 4)
    out[(size_t)(nb + i) * K + kb + tx] = tile[tx][i];
}

// ------------------------------------------------------------------
// LayerNorm rows of 1024, fp32 math
// ------------------------------------------------------------------
__device__ __forceinline__ void ln_body(const float (&v)[4], float s, float s2,
                                        const bf16* g, const bf16* b, bf16* yr, int tid) {
#pragma unroll
  for (int off = 32; off; off >>= 1) {
    s  += __shfl_down(s, off);
    s2 += __shfl_down(s2, off);
  }
  __shared__ float red[8];
  int w = tid >> 6;
  if ((tid & 63) == 0) { red[w] = s; red[4 + w] = s2; }
  __syncthreads();
  if (tid == 0) {
    red[0] = red[0] + red[1] + red[2] + red[3];
    red[4] = red[4] + red[5] + red[6] + red[7];
  }
  __syncthreads();
  float mu  = red[0] * (1.0f / CDIM);
  float var = fmaxf(red[4] * (1.0f / CDIM) - mu * mu, 0.f);
  float rstd = rsqrtf(var + 1e-5f);
#pragma unroll
  for (int i = 0; i < 4; i++) {
    int c = tid * 4 + i;
    yr[c] = (bf16)((v[i] - mu) * rstd * (float)g[c] + (float)b[c]);
  }
}

__global__ __launch_bounds__(256) void ln_any(const void* __restrict__ x,
                                              const int* __restrict__ flag,
                                              const bf16* __restrict__ g,
                                              const bf16* __restrict__ b,
                                              bf16* __restrict__ y) {
  int row = blockIdx.x, tid = threadIdx.x;
  bool isb = (*flag != 0);
  float v[4]; float s = 0.f, s2 = 0.f;
#pragma unroll
  for (int i = 0; i < 4; i++) {
    size_t idx = (size_t)row * CDIM + tid * 4 + i;
    float f = isb ? (float)((const bf16*)x)[idx] : ((const float*)x)[idx];
    v[i] = f; s += f; s2 += f * f;
  }
  ln_body(v, s, s2, g, b, y + (size_t)row * CDIM, tid);
}

__global__ __launch_bounds__(256) void ln_f32(const float* __restrict__ x,
                                              const bf16* __restrict__ g,
                                              const bf16* __restrict__ b,
                                              bf16* __restrict__ y) {
  int row = blockIdx.x, tid = threadIdx.x;
  float v[4]; float s = 0.f, s2 = 0.f;
#pragma unroll
  for (int i = 0; i < 4; i++) {
    float f = x[(size_t)row * CDIM + tid * 4 + i];
    v[i] = f; s += f; s2 += f * f;
  }
  ln_body(v, s, s2, g, b, y + (size_t)row * CDIM, tid);
}

// ------------------------------------------------------------------
// GEMM core, BK=64 (two BK=32 panels per barrier-pair -> 32 MFMAs per
// barrier for 128^2 tiles, half the barrier count of round 6).
// Panel LDS layout identical to proven round-6 pattern (XOR chunk swz).
// ------------------------------------------------------------------
template <int BM, int BN>
__device__ __forceinline__ void gemm_core(const bf16* __restrict__ A,
                                          const bf16* __restrict__ Bt,
                                          int K, int m0, int n0,
                                          bf16* As, bf16* Bs,
                                          f32x4 (&acc)[BM / 32][BN / 32]) {
  constexpr int SI = BM / 32, SJ = BN / 32;
  int t = threadIdx.x;
  int wave = t >> 6, lane = t & 63, quad = lane >> 4, l16 = lane & 15;
  int wm = (wave & 1) * (BM / 2), wn = (wave >> 1) * (BN / 2);
  int srow = t >> 2, sc = t & 3;
  int swz = (srow >> 1) & 3;
  const bf16* ga[BM / 64];
  const bf16* gb[BN / 64];
#pragma unroll
  for (int h = 0; h < BM / 64; h++)
    ga[h] = A + (size_t)(m0 + h * 64 + srow) * K + (sc ^ swz) * 8;
#pragma unroll
  for (int h = 0; h < BN / 64; h++)
    gb[h] = Bt + (size_t)(n0 + h * 64 + srow) * K + (sc ^ swz) * 8;

  for (int k0 = 0; k0 < K; k0 += 64) {
#pragma unroll
    for (int q = 0; q < 2; q++) {
#pragma unroll
      for (int h = 0; h < BM / 64; h++)
        glds16(ga[h] + k0 + q * 32, As + q * (BM * 32) + h * 2048 + srow * 32 + sc * 8);
#pragma unroll
      for (int h = 0; h < BN / 64; h++)
        glds16(gb[h] + k0 + q * 32, Bs + q * (BN * 32) + h * 2048 + srow * 32 + sc * 8);
    }
    __syncthreads();
#pragma unroll
    for (int q = 0; q < 2; q++) {
      bf16x8 af[SI], bfr[SJ];
#pragma unroll
      for (int i = 0; i < SI; i++) {
        int m = wm + i * 16 + l16;
        af[i] = *(const bf16x8*)&As[q * (BM * 32) + m * 32 + ((quad ^ ((m >> 1) & 3)) * 8)];
      }
#pragma unroll
      for (int j = 0; j < SJ; j++) {
        int n = wn + j * 16 + l16;
        bfr[j] = *(const bf16x8*)&Bs[q * (BN * 32) + n * 32 + ((quad ^ ((n >> 1) & 3)) * 8)];
      }
#pragma unroll
      for (int i = 0; i < SI; i++)
#pragma unroll
        for (int j = 0; j < SJ; j++)
          acc[i][j] = __builtin_amdgcn_mfma_f32_16x16x32_bf16(af[i], bfr[j], acc[i][j], 0, 0, 0);
    }
    __syncthreads();
  }
}

#define EPI_NONE 0
#define EPI_RES  1
#define EPI_GELU 2

template <int BM, int BN, int EPI, typename OutT, typename ResT>
__global__ __launch_bounds__(256) void gemm128(const bf16* __restrict__ A,
                                               const bf16* __restrict__ Bt,
                                               const bf16* __restrict__ bias,
                                               const ResT* __restrict__ res,
                                               OutT* __restrict__ C,
                                               int N, int K) {
  __shared__ alignas(16) bf16 As[2 * BM * 32];
  __shared__ alignas(16) bf16 Bs[2 * BN * 32];
  int m0 = blockIdx.y * BM, n0 = blockIdx.x * BN;
  f32x4 acc[BM / 32][BN / 32] = {};
  gemm_core<BM, BN>(A, Bt, K, m0, n0, As, Bs, acc);

  int t = threadIdx.x, wave = t >> 6, lane = t & 63, quad = lane >> 4, l16 = lane & 15;
  int wm = (wave & 1) * (BM / 2), wn = (wave >> 1) * (BN / 2);
#pragma unroll
  for (int i = 0; i < BM / 32; i++)
#pragma unroll
    for (int j = 0; j < BN / 32; j++) {
      int n = n0 + wn + j * 16 + l16;
      float bv = (float)bias[n];
#pragma unroll
      for (int r = 0; r < 4; r++) {
        int m = m0 + wm + i * 16 + quad * 4 + r;
        float v = acc[i][j][r] + bv;
        if (EPI == EPI_GELU)      v = 0.5f * v * (1.0f + erff(v * 0.70710678118654752f));
        else if (EPI == EPI_RES)  v += (float)res[(size_t)m * N + n];
        C[(size_t)m * N + n] = (OutT)v;
      }
    }
}

// QKV GEMM. Q cols (n<1024) pre-scaled by 1/8 (exact, pow2) so attention
// needs no score scaling. V cols (n>=2048) written transposed [d][token].
__global__ __launch_bounds__(256) void gemm_qkv(const bf16* __restrict__ A,
                                                const bf16* __restrict__ Bt,
                                                const bf16* __restrict__ bias,
                                                bf16* __restrict__ QK,
                                                bf16* __restrict__ Vt) {
  __shared__ alignas(16) bf16 As[2 * 128 * 32];
  __shared__ alignas(16) bf16 Bs[2 * 128 * 32];
  int m0 = blockIdx.y * 128, n0 = blockIdx.x * 128;
  f32x4 acc[4][4] = {};
  gemm_core<128, 128>(A, Bt, 1024, m0, n0, As, Bs, acc);

  int t = threadIdx.x, wave = t >> 6, lane = t & 63, quad = lane >> 4, l16 = lane & 15;
  int wm = (wave & 1) * 64, wn = (wave >> 1) * 64;
#pragma unroll
  for (int i = 0; i < 4; i++)
#pragma unroll
    for (int j = 0; j < 4; j++) {
      int n = n0 + wn + j * 16 + l16;
      float bv = (float)bias[n];
      int mb = m0 + wm + i * 16 + quad * 4;
      if (n < 1024) {
#pragma unroll
        for (int r = 0; r < 4; r++)
          QK[(size_t)(mb + r) * 2048 + n] = (bf16)((acc[i][j][r] + bv) * 0.125f);
      } else if (n < 2048) {
#pragma unroll
        for (int r = 0; r < 4; r++)
          QK[(size_t)(mb + r) * 2048 + n] = (bf16)(acc[i][j][r] + bv);
      } else {
        bf16x4 pk;
#pragma unroll
        for (int r = 0; r < 4; r++) pk[r] = (bf16)(acc[i][j][r] + bv);
        *(bf16x4*)&Vt[(size_t)(n - 2048) * TOKENS + mb] = pk;
      }
    }
}

// ------------------------------------------------------------------
// Flash attention v4: 512 threads (8 waves), Q-tile 128, 64-key tiles,
// shuffle-free softmax (shift-invariance; row sums via ones-MFMA),
// double-buffered K/V glds staging. LDS ~50KB -> 3 blocks/CU.
// ------------------------------------------------------------------
__global__ __launch_bounds__(512) void attn_kernel(const bf16* __restrict__ QK,
                                                   const bf16* __restrict__ Vt,
                                                   bf16* __restrict__ O) {
  __shared__ alignas(16) bf16 Ks[2][4096];      // [key][d] 64x64, swizzled
  __shared__ alignas(16) bf16 Vs[2][4096];      // [d][key] 64x64, swizzled
  __shared__ alignas(16) bf16 Ps[8][16 * 72];   // per-wave P [qrow][key], padded
  int b = blockIdx.z, h = blockIdx.y, q0 = blockIdx.x * 128;
  int t = threadIdx.x, wave = t >> 6, lane = t & 63, quad = lane >> 4, l16 = lane & 15;

  const bf16* Qg = QK;
  const bf16* Kg = QK + 1024;
  const size_t bT = (size_t)b * TSEQ;
  const int h64 = h * 64;

  // staging: wave w stages rows w*8..w*8+7 (1 glds16/thread/matrix/iter)
  int srow = wave * 8 + (lane >> 3);
  int schunk = (lane & 7) ^ (srow & 7);

  bf16x8 aq0, aq1;
  {
    size_t qrow = bT + q0 + wave * 16 + l16;
    aq0 = *(const bf16x8*)&Qg[qrow * 2048 + h64 + quad * 8];
    aq1 = *(const bf16x8*)&Qg[qrow * 2048 + h64 + 32 + quad * 8];
  }

  f32x4 accO[4] = {};
  f32x4 accL = {};

  auto stage = [&](int tile, int buf) {
    glds16(&Kg[(bT + tile * 64 + srow) * 2048 + h64 + schunk * 8],
           &Ks[buf][wave * 512 + lane * 8]);
    glds16(&Vt[(size_t)(h64 + srow) * TOKENS + bT + tile * 64 + schunk * 8],
           &Vs[buf][wave * 512 + lane * 8]);
  };

  const bf16 one = (bf16)1.0f;
  const bf16x8 onesv = {one, one, one, one, one, one, one, one};
  int sw = l16 & 7;
  bf16* Pw = &Ps[wave][0];

  stage(0, 0);
  __syncthreads();

  for (int it = 0; it < TSEQ / 64; it++) {
    int cur = it & 1;
    if (it + 1 < TSEQ / 64) stage(it + 1, cur ^ 1);

    const bf16* KsC = &Ks[cur][0];
    const bf16* VsC = &Vs[cur][0];

    // S = Q K^T (scores pre-scaled via Q)
    f32x4 S[4];
#pragma unroll
    for (int c = 0; c < 4; c++) {
      int row = c * 16 + l16;
      bf16x8 kb0 = *(const bf16x8*)&KsC[row * 64 + ((quad ^ sw) * 8)];
      bf16x8 kb1 = *(const bf16x8*)&KsC[row * 64 + (((quad + 4) ^ sw) * 8)];
      f32x4 s = {};
      s = __builtin_amdgcn_mfma_f32_16x16x32_bf16(aq0, kb0, s, 0, 0, 0);
      s = __builtin_amdgcn_mfma_f32_16x16x32_bf16(aq1, kb1, s, 0, 0, 0);
      S[c] = s;
    }

    // P = exp(S), per-wave LDS round-trip to A-layout
#pragma unroll
    for (int c = 0; c < 4; c++)
#pragma unroll
      for (int r = 0; r < 4; r++)
        Pw[(quad * 4 + r) * 72 + c * 16 + l16] = (bf16)__expf(fminf(S[c][r], 60.f));

    bf16x8 pa0 = *(const bf16x8*)&Pw[l16 * 72 + quad * 8];
    bf16x8 pa1 = *(const bf16x8*)&Pw[l16 * 72 + 32 + quad * 8];
#pragma unroll
    for (int ds = 0; ds < 4; ds++) {
      int row = ds * 16 + l16;
      bf16x8 vb0 = *(const bf16x8*)&VsC[row * 64 + ((quad ^ sw) * 8)];
      bf16x8 vb1 = *(const bf16x8*)&VsC[row * 64 + (((quad + 4) ^ sw) * 8)];
      accO[ds] = __builtin_amdgcn_mfma_f32_16x16x32_bf16(pa0, vb0, accO[ds], 0, 0, 0);
      accO[ds] = __builtin_amdgcn_mfma_f32_16x16x32_bf16(pa1, vb1, accO[ds], 0, 0, 0);
    }
    accL = __builtin_amdgcn_mfma_f32_16x16x32_bf16(pa0, onesv, accL, 0, 0, 0);
    accL = __builtin_amdgcn_mfma_f32_16x16x32_bf16(pa1, onesv, accL, 0, 0, 0);

    __syncthreads();
  }

#pragma unroll
  for (int ds = 0; ds < 4; ds++)
#pragma unroll
    for (int r = 0; r < 4; r++) {
      float v = accO[ds][r] / fmaxf(accL[r], 1e-30f);
      O[(bT + q0 + wave * 16 + quad * 4 + r) * CDIM + h64 + ds * 16 + l16] = (bf16)v;
    }
}

// ------------------------------------------------------------------
extern "C" void kernel_launch(void* const* d_in, const int* in_sizes, int n_in,
                              void* d_out, int out_size, void* d_ws, size_t ws_size,
                              hipStream_t stream) {
  char* ws = (char*)d_ws;
  const size_t MB = 1024 * 1024;
  const size_t KB = 1024;

  int* flags = (int*)ws;
  bf16* vec_c = (bf16*)(ws + 4 * KB);
  bf16* ln1g_c = vec_c + 0 * 8192;
  bf16* ln1b_c = vec_c + 1 * 8192;
  bf16* ln2g_c = vec_c + 2 * 8192;
  bf16* ln2b_c = vec_c + 3 * 8192;
  bf16* bqkv_c = vec_c + 4 * 8192;            // [3072]: bq | bk | bv
  bf16* bo_c   = vec_c + 6 * 8192;
  bf16* b1_c   = vec_c + 7 * 8192;
  bf16* b2_c   = vec_c + 8 * 8192;

  bf16*  WqkvT  = (bf16*)(ws + 1 * MB);       // [3072][1024]  1-7
  bf16*  WoT    = (bf16*)(ws + 7 * MB);       // 7-9
  bf16*  W1T    = (bf16*)(ws + 9 * MB);       // 9-17
  bf16*  W2T    = (bf16*)(ws + 17 * MB);      // 17-25
  bf16*  xn     = (bf16*)(ws + 25 * MB);      // 25-33  (live until Wo GEMM)
  bf16*  QKbuf  = (bf16*)(ws + 33 * MB);      // [4096][2048] 33-49 (dead after attn)
  bf16*  Vtbuf  = (bf16*)(ws + 49 * MB);      // [1024][4096] 49-57 (dead after attn)
  bf16*  ab     = (bf16*)(ws + 57 * MB);      // 57-65 (dead after Wo GEMM)
  float* xmid32 = (float*)(ws + 65 * MB);     // 65-81 fp32
  bf16*  h2     = (bf16*)(ws + 81 * MB);      // 81-89
  bf16*  f1     = (bf16*)(ws + 33 * MB);      // [4096][4096] 33-65 (reuses dead bufs)

  // ---- detect dtypes ----
  // flag idx: 0 x,1 ln1g,2 ln1b,3 ln2g,4 ln2b,5 Wq,6 bq,7 Wk,8 bk,9 Wv,10 bv,
  //           11 Wo,12 bo,13 W1,14 b1,15 W2,16 b2
  const int din_idx[NBUF] = {0, 2, 3, 4, 5, 6, 7, 8, 9, 10, 11, 12, 13, 14, 15, 16, 17};
  DetectArgs da;
  for (int i = 0; i < NBUF; i++) { da.p[i] = d_in[din_idx[i]]; da.n[i] = in_sizes[din_idx[i]]; }
  detect_kernel<<<NBUF, 256, 0, stream>>>(da, flags);

  // ---- all small vectors in one launch ----
  VecCvt vc;
  {
    const int vf[10] = {1, 2, 3, 4, 6, 8, 10, 12, 14, 16};
    bf16* vd[10] = {ln1g_c, ln1b_c, ln2g_c, ln2b_c,
                    bqkv_c, bqkv_c + 1024, bqkv_c + 2048, bo_c, b1_c, b2_c};
    for (int i = 0; i < 10; i++) {
      int di = din_idx[vf[i]];
      vc.p[i] = d_in[di]; vc.d[i] = vd[i]; vc.n[i] = in_sizes[di]; vc.fi[i] = vf[i];
    }
  }
  convert_vecs<<<10, 256, 0, stream>>>(vc, flags);

  // ---- transpose weights (convert fused) ----
  dim3 tb(64, 4);
  transpose_any<<<dim3(16, 16), tb, 0, stream>>>(d_in[6],  WqkvT,                   1024, 1024, flags + 5);
  transpose_any<<<dim3(16, 16), tb, 0, stream>>>(d_in[8],  WqkvT + 1024 * 1024,     1024, 1024, flags + 7);
  transpose_any<<<dim3(16, 16), tb, 0, stream>>>(d_in[10], WqkvT + 2 * 1024 * 1024, 1024, 1024, flags + 9);
  transpose_any<<<dim3(16, 16), tb, 0, stream>>>(d_in[12], WoT, 1024, 1024, flags + 11);
  transpose_any<<<dim3(64, 16), tb, 0, stream>>>(d_in[14], W1T, 1024, 4096, flags + 13);
  transpose_any<<<dim3(16, 64), tb, 0, stream>>>(d_in[16], W2T, 4096, 1024, flags + 15);

  // ---- pipeline ----
  ln_any<<<TOKENS, 256, 0, stream>>>(d_in[0], flags + 0, ln1g_c, ln1b_c, xn);

  gemm_qkv<<<dim3(24, 32), 256, 0, stream>>>(xn, WqkvT, bqkv_c, QKbuf, Vtbuf);

  attn_kernel<<<dim3(TSEQ / 128, NHEADS, 2), 512, 0, stream>>>(QKbuf, Vtbuf, ab);

  gemm128<64, 128, EPI_RES, float, bf16><<<dim3(8, 64), 256, 0, stream>>>(
      ab, WoT, bo_c, xn, xmid32, 1024, 1024);

  ln_f32<<<TOKENS, 256, 0, stream>>>(xmid32, ln2g_c, ln2b_c, h2);

  gemm128<128, 128, EPI_GELU, bf16, bf16><<<dim3(32, 32), 256, 0, stream>>>(
      h2, W1T, b1_c, (const bf16*)nullptr, f1, 4096, 1024);

  gemm128<64, 128, EPI_RES, float, float><<<dim3(8, 64), 256, 0, stream>>>(
      f1, W2T, b2_c, xmid32, (float*)d_out, 1024, 4096);
}

// Round 9
// 395.798 us; speedup vs baseline: 1.8188x; 1.1463x over previous
//
#include <hip/hip_runtime.h>
#include <cstdint>
#include <cstddef>

typedef __bf16 bf16;
typedef __bf16 bf16x8 __attribute__((ext_vector_type(8)));
typedef __bf16 bf16x4 __attribute__((ext_vector_type(4)));
typedef float f32x4 __attribute__((ext_vector_type(4)));

#define TOKENS 4096   // B*T
#define TSEQ   2048
#define NHEADS 16
#define HDIM   64
#define CDIM   1024

// ---- async global->LDS, 16B per lane ----
typedef __attribute__((address_space(3))) unsigned int lds_uint;
typedef __attribute__((address_space(1))) const unsigned int g_uint;
__device__ __forceinline__ void glds16(const bf16* g, bf16* l) {
  __builtin_amdgcn_global_load_lds((g_uint*)g, (lds_uint*)l, 16, 0, 0);
}

// fast GELU: x*sigmoid(1.5957691x + 0.0713548x^3); max dev from erf-GELU ~3e-4
__device__ __forceinline__ float gelu_f(float v) {
  float g2 = v * (1.5957691216f + 0.0713548163f * v * v);
  return v / (1.0f + __expf(-g2));
}

// ------------------------------------------------------------------
// Input dtype detection (insurance; fp32 -> flag 0). See round-2 note.
// ------------------------------------------------------------------
#define NBUF 17
struct DetectArgs { const void* p[NBUF]; int n[NBUF]; };

__global__ __launch_bounds__(256) void detect_kernel(DetectArgs a, int* __restrict__ flags) {
  __shared__ int s_nz, s_bl;
  if (threadIdx.x == 0) { s_nz = 0; s_bl = 0; }
  __syncthreads();
  int i = blockIdx.x;
  const unsigned int* w = (const unsigned int*)a.p[i];
  int nwords = a.n[i] / 2; if (nwords > 2048) nwords = 2048;
  int nz = 0, bl = 0;
  for (int j = threadIdx.x; j < nwords; j += 256) {
    unsigned int v = w[j];
    if (v != 0u) {
      nz++;
      unsigned int e = (v >> 7) & 0xFFu;
      if (e >= 100u && e <= 140u) bl++;
    }
  }
  atomicAdd(&s_nz, nz);
  atomicAdd(&s_bl, bl);
  __syncthreads();
  if (threadIdx.x == 0) flags[i] = (2 * s_bl >= s_nz) ? 1 : 0;
}

__device__ __forceinline__ float ld_any(const void* p, size_t idx, bool isb) {
  return isb ? (float)((const bf16*)p)[idx] : ((const float*)p)[idx];
}

// ------------------------------------------------------------------
// LayerNorm stats (rows of 1024, 256 threads): returns mu, rstd
// ------------------------------------------------------------------
__device__ __forceinline__ void ln_stats(float s, float s2, int tid, float& mu, float& rstd) {
#pragma unroll
  for (int off = 32; off; off >>= 1) {
    s  += __shfl_down(s, off);
    s2 += __shfl_down(s2, off);
  }
  __shared__ float red[8];
  int w = tid >> 6;
  if ((tid & 63) == 0) { red[w] = s; red[4 + w] = s2; }
  __syncthreads();
  if (tid == 0) {
    red[0] = red[0] + red[1] + red[2] + red[3];
    red[4] = red[4] + red[5] + red[6] + red[7];
  }
  __syncthreads();
  mu = red[0] * (1.0f / CDIM);
  float var = fmaxf(red[4] * (1.0f / CDIM) - mu * mu, 0.f);
  rstd = rsqrtf(var + 1e-5f);
}

__global__ __launch_bounds__(256) void ln_f32(const float* __restrict__ x,
                                              const bf16* __restrict__ g,
                                              const bf16* __restrict__ b,
                                              bf16* __restrict__ y) {
  int row = blockIdx.x, tid = threadIdx.x;
  float v[4]; float s = 0.f, s2 = 0.f;
#pragma unroll
  for (int i = 0; i < 4; i++) {
    float f = x[(size_t)row * CDIM + tid * 4 + i];
    v[i] = f; s += f; s2 += f * f;
  }
  float mu, rstd;
  ln_stats(s, s2, tid, mu, rstd);
  bf16* yr = y + (size_t)row * CDIM;
#pragma unroll
  for (int i = 0; i < 4; i++) {
    int c = tid * 4 + i;
    yr[c] = (bf16)((v[i] - mu) * rstd * (float)g[c] + (float)b[c]);
  }
}

// ------------------------------------------------------------------
// Mega preprocessing kernel (ONE launch): 6 weight transposes (+convert),
// 10 small-vector converts, LN1 over 4096 rows.
// RACE-FIX (round 8 post-mortem): LN1 reads gamma/beta from RAW inputs
// (a.graw/a.braw, dtype via flags) — NOT from same-launch convert output.
// All branches depend only on flags/d_in (previous launches).
// Blocks: [0,3072) transposes, 3072 vec-converts, (3072, 3072+4096] LN1.
// ------------------------------------------------------------------
struct MegaArgs {
  const void* w_in[6]; bf16* w_out[6]; int wK[6], wN[6], wflag[6];
  const void* vp[10]; bf16* vd[10]; int vn[10], vfi[10];
  const void* x; const void* graw; const void* braw; bf16* y;
};

__global__ __launch_bounds__(256) void mega_pre(MegaArgs a, const int* __restrict__ flags) {
  int bid = blockIdx.x;
  int tx = threadIdx.x, ty = threadIdx.y;          // blockDim (64,4)
  int tid = tx + ty * 64;
  if (bid < 3072) {
    __shared__ bf16 tile[64][65];
    int mi, start;
    if (bid < 1024)      { mi = bid >> 8; start = mi << 8; }
    else if (bid < 2048) { mi = 4; start = 1024; }
    else                 { mi = 5; start = 2048; }
    int tb = bid - start;
    int nT = a.wN[mi] >> 6;
    int kb = (tb / nT) * 64, nb = (tb % nT) * 64;
    int K = a.wK[mi], N = a.wN[mi];
    bool isb = flags[a.wflag[mi]] != 0;
    const void* in = a.w_in[mi]; bf16* out = a.w_out[mi];
    for (int i = ty; i < 64; i += 4)
      tile[i][tx] = (bf16)ld_any(in, (size_t)(kb + i) * N + nb + tx, isb);
    __syncthreads();
    for (int i = ty; i < 64; i += 4)
      out[(size_t)(nb + i) * K + kb + tx] = tile[tx][i];
  } else if (bid == 3072) {
    for (int i = 0; i < 10; i++) {
      bool isb = flags[a.vfi[i]] != 0;
      const void* in = a.vp[i]; bf16* out = a.vd[i]; int n = a.vn[i];
      for (int j = tid; j < n; j += 256)
        out[j] = (bf16)ld_any(in, j, isb);
    }
  } else {
    int row = bid - 3073;
    bool isb  = flags[0] != 0;
    bool gisb = flags[1] != 0;
    bool bisb = flags[2] != 0;
    float v[4]; float s = 0.f, s2 = 0.f;
#pragma unroll
    for (int i = 0; i < 4; i++) {
      float f = ld_any(a.x, (size_t)row * CDIM + tid * 4 + i, isb);
      v[i] = f; s += f; s2 += f * f;
    }
    float mu, rstd;
    ln_stats(s, s2, tid, mu, rstd);
    bf16* yr = a.y + (size_t)row * CDIM;
#pragma unroll
    for (int i = 0; i < 4; i++) {
      int c = tid * 4 + i;
      float gv = ld_any(a.graw, c, gisb);
      float bv = ld_any(a.braw, c, bisb);
      yr[c] = (bf16)((v[i] - mu) * rstd * gv + bv);
    }
  }
}

// ------------------------------------------------------------------
// GEMM core, BK=64 (two BK=32 panels per barrier-pair), glds staging,
// XOR-chunk swizzle (proven round 6/7)
// ------------------------------------------------------------------
template <int BM, int BN>
__device__ __forceinline__ void gemm_core(const bf16* __restrict__ A,
                                          const bf16* __restrict__ Bt,
                                          int K, int m0, int n0,
                                          bf16* As, bf16* Bs,
                                          f32x4 (&acc)[BM / 32][BN / 32]) {
  constexpr int SI = BM / 32, SJ = BN / 32;
  int t = threadIdx.x;
  int wave = t >> 6, lane = t & 63, quad = lane >> 4, l16 = lane & 15;
  int wm = (wave & 1) * (BM / 2), wn = (wave >> 1) * (BN / 2);
  int srow = t >> 2, sc = t & 3;
  int swz = (srow >> 1) & 3;
  const bf16* ga[BM / 64];
  const bf16* gb[BN / 64];
#pragma unroll
  for (int h = 0; h < BM / 64; h++)
    ga[h] = A + (size_t)(m0 + h * 64 + srow) * K + (sc ^ swz) * 8;
#pragma unroll
  for (int h = 0; h < BN / 64; h++)
    gb[h] = Bt + (size_t)(n0 + h * 64 + srow) * K + (sc ^ swz) * 8;

  for (int k0 = 0; k0 < K; k0 += 64) {
#pragma unroll
    for (int q = 0; q < 2; q++) {
#pragma unroll
      for (int h = 0; h < BM / 64; h++)
        glds16(ga[h] + k0 + q * 32, As + q * (BM * 32) + h * 2048 + srow * 32 + sc * 8);
#pragma unroll
      for (int h = 0; h < BN / 64; h++)
        glds16(gb[h] + k0 + q * 32, Bs + q * (BN * 32) + h * 2048 + srow * 32 + sc * 8);
    }
    __syncthreads();
#pragma unroll
    for (int q = 0; q < 2; q++) {
      bf16x8 af[SI], bfr[SJ];
#pragma unroll
      for (int i = 0; i < SI; i++) {
        int m = wm + i * 16 + l16;
        af[i] = *(const bf16x8*)&As[q * (BM * 32) + m * 32 + ((quad ^ ((m >> 1) & 3)) * 8)];
      }
#pragma unroll
      for (int j = 0; j < SJ; j++) {
        int n = wn + j * 16 + l16;
        bfr[j] = *(const bf16x8*)&Bs[q * (BN * 32) + n * 32 + ((quad ^ ((n >> 1) & 3)) * 8)];
      }
#pragma unroll
      for (int i = 0; i < SI; i++)
#pragma unroll
        for (int j = 0; j < SJ; j++)
          acc[i][j] = __builtin_amdgcn_mfma_f32_16x16x32_bf16(af[i], bfr[j], acc[i][j], 0, 0, 0);
    }
    __syncthreads();
  }
}

#define EPI_NONE 0
#define EPI_RES  1
#define EPI_GELU 2

template <int BM, int BN, int EPI, typename OutT, typename ResT>
__global__ __launch_bounds__(256) void gemm128(const bf16* __restrict__ A,
                                               const bf16* __restrict__ Bt,
                                               const bf16* __restrict__ bias,
                                               const ResT* __restrict__ res,
                                               OutT* __restrict__ C,
                                               int N, int K) {
  __shared__ alignas(16) bf16 As[2 * BM * 32];
  __shared__ alignas(16) bf16 Bs[2 * BN * 32];
  int m0 = blockIdx.y * BM, n0 = blockIdx.x * BN;
  f32x4 acc[BM / 32][BN / 32] = {};
  gemm_core<BM, BN>(A, Bt, K, m0, n0, As, Bs, acc);

  int t = threadIdx.x, wave = t >> 6, lane = t & 63, quad = lane >> 4, l16 = lane & 15;
  int wm = (wave & 1) * (BM / 2), wn = (wave >> 1) * (BN / 2);
#pragma unroll
  for (int i = 0; i < BM / 32; i++)
#pragma unroll
    for (int j = 0; j < BN / 32; j++) {
      int n = n0 + wn + j * 16 + l16;
      float bv = (float)bias[n];
#pragma unroll
      for (int r = 0; r < 4; r++) {
        int m = m0 + wm + i * 16 + quad * 4 + r;
        float v = acc[i][j][r] + bv;
        if (EPI == EPI_GELU)      v = gelu_f(v);
        else if (EPI == EPI_RES)  v += (float)res[(size_t)m * N + n];
        C[(size_t)m * N + n] = (OutT)v;
      }
    }
}

// QKV GEMM. Q cols (n<1024) pre-scaled by 1/8 (exact, pow2) so attention
// needs no score scaling. V cols (n>=2048) written transposed [d][token].
__global__ __launch_bounds__(256) void gemm_qkv(const bf16* __restrict__ A,
                                                const bf16* __restrict__ Bt,
                                                const bf16* __restrict__ bias,
                                                bf16* __restrict__ QK,
                                                bf16* __restrict__ Vt) {
  __shared__ alignas(16) bf16 As[2 * 128 * 32];
  __shared__ alignas(16) bf16 Bs[2 * 128 * 32];
  int m0 = blockIdx.y * 128, n0 = blockIdx.x * 128;
  f32x4 acc[4][4] = {};
  gemm_core<128, 128>(A, Bt, 1024, m0, n0, As, Bs, acc);

  int t = threadIdx.x, wave = t >> 6, lane = t & 63, quad = lane >> 4, l16 = lane & 15;
  int wm = (wave & 1) * 64, wn = (wave >> 1) * 64;
#pragma unroll
  for (int i = 0; i < 4; i++)
#pragma unroll
    for (int j = 0; j < 4; j++) {
      int n = n0 + wn + j * 16 + l16;
      float bv = (float)bias[n];
      int mb = m0 + wm + i * 16 + quad * 4;
      if (n < 1024) {
#pragma unroll
        for (int r = 0; r < 4; r++)
          QK[(size_t)(mb + r) * 2048 + n] = (bf16)((acc[i][j][r] + bv) * 0.125f);
      } else if (n < 2048) {
#pragma unroll
        for (int r = 0; r < 4; r++)
          QK[(size_t)(mb + r) * 2048 + n] = (bf16)(acc[i][j][r] + bv);
      } else {
        bf16x4 pk;
#pragma unroll
        for (int r = 0; r < 4; r++) pk[r] = (bf16)(acc[i][j][r] + bv);
        *(bf16x4*)&Vt[(size_t)(n - 2048) * TOKENS + mb] = pk;
      }
    }
}

// ------------------------------------------------------------------
// Flash attention v4 (round 7, unchanged): 8 waves, Q-tile 128,
// shuffle-free softmax, double-buffered glds K/V staging.
// ------------------------------------------------------------------
__global__ __launch_bounds__(512) void attn_kernel(const bf16* __restrict__ QK,
                                                   const bf16* __restrict__ Vt,
                                                   bf16* __restrict__ O) {
  __shared__ alignas(16) bf16 Ks[2][4096];
  __shared__ alignas(16) bf16 Vs[2][4096];
  __shared__ alignas(16) bf16 Ps[8][16 * 72];
  int b = blockIdx.z, h = blockIdx.y, q0 = blockIdx.x * 128;
  int t = threadIdx.x, wave = t >> 6, lane = t & 63, quad = lane >> 4, l16 = lane & 15;

  const bf16* Qg = QK;
  const bf16* Kg = QK + 1024;
  const size_t bT = (size_t)b * TSEQ;
  const int h64 = h * 64;

  int srow = wave * 8 + (lane >> 3);
  int schunk = (lane & 7) ^ (srow & 7);

  bf16x8 aq0, aq1;
  {
    size_t qrow = bT + q0 + wave * 16 + l16;
    aq0 = *(const bf16x8*)&Qg[qrow * 2048 + h64 + quad * 8];
    aq1 = *(const bf16x8*)&Qg[qrow * 2048 + h64 + 32 + quad * 8];
  }

  f32x4 accO[4] = {};
  f32x4 accL = {};

  auto stage = [&](int tile, int buf) {
    glds16(&Kg[(bT + tile * 64 + srow) * 2048 + h64 + schunk * 8],
           &Ks[buf][wave * 512 + lane * 8]);
    glds16(&Vt[(size_t)(h64 + srow) * TOKENS + bT + tile * 64 + schunk * 8],
           &Vs[buf][wave * 512 + lane * 8]);
  };

  const bf16 one = (bf16)1.0f;
  const bf16x8 onesv = {one, one, one, one, one, one, one, one};
  int sw = l16 & 7;
  bf16* Pw = &Ps[wave][0];

  stage(0, 0);
  __syncthreads();

  for (int it = 0; it < TSEQ / 64; it++) {
    int cur = it & 1;
    if (it + 1 < TSEQ / 64) stage(it + 1, cur ^ 1);

    const bf16* KsC = &Ks[cur][0];
    const bf16* VsC = &Vs[cur][0];

    f32x4 S[4];
#pragma unroll
    for (int c = 0; c < 4; c++) {
      int row = c * 16 + l16;
      bf16x8 kb0 = *(const bf16x8*)&KsC[row * 64 + ((quad ^ sw) * 8)];
      bf16x8 kb1 = *(const bf16x8*)&KsC[row * 64 + (((quad + 4) ^ sw) * 8)];
      f32x4 s = {};
      s = __builtin_amdgcn_mfma_f32_16x16x32_bf16(aq0, kb0, s, 0, 0, 0);
      s = __builtin_amdgcn_mfma_f32_16x16x32_bf16(aq1, kb1, s, 0, 0, 0);
      S[c] = s;
    }

#pragma unroll
    for (int c = 0; c < 4; c++)
#pragma unroll
      for (int r = 0; r < 4; r++)
        Pw[(quad * 4 + r) * 72 + c * 16 + l16] = (bf16)__expf(fminf(S[c][r], 60.f));

    bf16x8 pa0 = *(const bf16x8*)&Pw[l16 * 72 + quad * 8];
    bf16x8 pa1 = *(const bf16x8*)&Pw[l16 * 72 + 32 + quad * 8];
#pragma unroll
    for (int ds = 0; ds < 4; ds++) {
      int row = ds * 16 + l16;
      bf16x8 vb0 = *(const bf16x8*)&VsC[row * 64 + ((quad ^ sw) * 8)];
      bf16x8 vb1 = *(const bf16x8*)&VsC[row * 64 + (((quad + 4) ^ sw) * 8)];
      accO[ds] = __builtin_amdgcn_mfma_f32_16x16x32_bf16(pa0, vb0, accO[ds], 0, 0, 0);
      accO[ds] = __builtin_amdgcn_mfma_f32_16x16x32_bf16(pa1, vb1, accO[ds], 0, 0, 0);
    }
    accL = __builtin_amdgcn_mfma_f32_16x16x32_bf16(pa0, onesv, accL, 0, 0, 0);
    accL = __builtin_amdgcn_mfma_f32_16x16x32_bf16(pa1, onesv, accL, 0, 0, 0);

    __syncthreads();
  }

#pragma unroll
  for (int ds = 0; ds < 4; ds++)
#pragma unroll
    for (int r = 0; r < 4; r++) {
      float v = accO[ds][r] / fmaxf(accL[r], 1e-30f);
      O[(bT + q0 + wave * 16 + quad * 4 + r) * CDIM + h64 + ds * 16 + l16] = (bf16)v;
    }
}

// ------------------------------------------------------------------
extern "C" void kernel_launch(void* const* d_in, const int* in_sizes, int n_in,
                              void* d_out, int out_size, void* d_ws, size_t ws_size,
                              hipStream_t stream) {
  char* ws = (char*)d_ws;
  const size_t MB = 1024 * 1024;
  const size_t KB = 1024;

  int* flags = (int*)ws;
  bf16* vec_c = (bf16*)(ws + 4 * KB);
  bf16* ln1g_c = vec_c + 0 * 8192;
  bf16* ln1b_c = vec_c + 1 * 8192;
  bf16* ln2g_c = vec_c + 2 * 8192;
  bf16* ln2b_c = vec_c + 3 * 8192;
  bf16* bqkv_c = vec_c + 4 * 8192;            // [3072]: bq | bk | bv
  bf16* bo_c   = vec_c + 6 * 8192;
  bf16* b1_c   = vec_c + 7 * 8192;
  bf16* b2_c   = vec_c + 8 * 8192;

  bf16*  WqkvT  = (bf16*)(ws + 1 * MB);       // [3072][1024]  1-7
  bf16*  WoT    = (bf16*)(ws + 7 * MB);       // 7-9
  bf16*  W1T    = (bf16*)(ws + 9 * MB);       // 9-17
  bf16*  W2T    = (bf16*)(ws + 17 * MB);      // 17-25
  bf16*  xn     = (bf16*)(ws + 25 * MB);      // 25-33  (live until Wo GEMM)
  bf16*  QKbuf  = (bf16*)(ws + 33 * MB);      // [4096][2048] 33-49 (dead after attn)
  bf16*  Vtbuf  = (bf16*)(ws + 49 * MB);      // [1024][4096] 49-57 (dead after attn)
  bf16*  ab     = (bf16*)(ws + 57 * MB);      // 57-65 (dead after Wo GEMM)
  float* xmid32 = (float*)(ws + 65 * MB);     // 65-81 fp32
  bf16*  h2     = (bf16*)(ws + 81 * MB);      // 81-89
  bf16*  f1     = (bf16*)(ws + 33 * MB);      // [4096][4096] 33-65 (reuses dead bufs)

  // flag idx: 0 x,1 ln1g,2 ln1b,3 ln2g,4 ln2b,5 Wq,6 bq,7 Wk,8 bk,9 Wv,10 bv,
  //           11 Wo,12 bo,13 W1,14 b1,15 W2,16 b2
  const int din_idx[NBUF] = {0, 2, 3, 4, 5, 6, 7, 8, 9, 10, 11, 12, 13, 14, 15, 16, 17};
  DetectArgs da;
  for (int i = 0; i < NBUF; i++) { da.p[i] = d_in[din_idx[i]]; da.n[i] = in_sizes[din_idx[i]]; }
  detect_kernel<<<NBUF, 256, 0, stream>>>(da, flags);

  // ---- mega preprocessing: transposes + vec converts + LN1, one launch ----
  MegaArgs ma;
  {
    const void* wi[6] = {d_in[6], d_in[8], d_in[10], d_in[12], d_in[14], d_in[16]};
    bf16* wo[6] = {WqkvT, WqkvT + 1024 * 1024, WqkvT + 2 * 1024 * 1024, WoT, W1T, W2T};
    const int wK[6] = {1024, 1024, 1024, 1024, 1024, 4096};
    const int wN[6] = {1024, 1024, 1024, 1024, 4096, 1024};
    const int wf[6] = {5, 7, 9, 11, 13, 15};
    for (int i = 0; i < 6; i++) {
      ma.w_in[i] = wi[i]; ma.w_out[i] = wo[i];
      ma.wK[i] = wK[i]; ma.wN[i] = wN[i]; ma.wflag[i] = wf[i];
    }
    const int vf[10] = {1, 2, 3, 4, 6, 8, 10, 12, 14, 16};
    bf16* vd[10] = {ln1g_c, ln1b_c, ln2g_c, ln2b_c,
                    bqkv_c, bqkv_c + 1024, bqkv_c + 2048, bo_c, b1_c, b2_c};
    for (int i = 0; i < 10; i++) {
      int di = din_idx[vf[i]];
      ma.vp[i] = d_in[di]; ma.vd[i] = vd[i]; ma.vn[i] = in_sizes[di]; ma.vfi[i] = vf[i];
    }
    ma.x = d_in[0]; ma.graw = d_in[2]; ma.braw = d_in[3]; ma.y = xn;
  }
  mega_pre<<<3072 + 1 + TOKENS, dim3(64, 4), 0, stream>>>(ma, flags);

  // ---- pipeline ----
  gemm_qkv<<<dim3(24, 32), 256, 0, stream>>>(xn, WqkvT, bqkv_c, QKbuf, Vtbuf);

  attn_kernel<<<dim3(TSEQ / 128, NHEADS, 2), 512, 0, stream>>>(QKbuf, Vtbuf, ab);

  gemm128<64, 128, EPI_RES, float, bf16><<<dim3(8, 64), 256, 0, stream>>>(
      ab, WoT, bo_c, xn, xmid32, 1024, 1024);

  ln_f32<<<TOKENS, 256, 0, stream>>>(xmid32, ln2g_c, ln2b_c, h2);

  gemm128<128, 128, EPI_GELU, bf16, bf16><<<dim3(32, 32), 256, 0, stream>>>(
      h2, W1T, b1_c, (const bf16*)nullptr, f1, 4096, 1024);

  gemm128<64, 128, EPI_RES, float, float><<<dim3(8, 64), 256, 0, stream>>>(
      f1, W2T, b2_c, xmid32, (float*)d_out, 1024, 4096);
}